// Round 4
// baseline (541.413 us; speedup 1.0000x reference)
//
#include <hip/hip_runtime.h>
#include <stdint.h>

#define LL 1024
#define NB 8
#define EE 1024
#define HH 16
#define DD 64
#define MM (LL*NB)      // 8192 rows (l*NB+n)
#define K3 (3*EE)       // 3072

typedef __attribute__((ext_vector_type(8))) short bf16x8;   // 8 bf16 in 4 VGPRs
typedef __attribute__((ext_vector_type(4))) float f32x4;
typedef __attribute__((ext_vector_type(4))) unsigned short u16x4;

__device__ __forceinline__ unsigned short f2bf(float f) {
  uint32_t u = __builtin_bit_cast(uint32_t, f);
  u += 0x7fffu + ((u >> 16) & 1u);           // RNE
  return (unsigned short)(u >> 16);
}
__device__ __forceinline__ f32x4 mfma16(bf16x8 a, bf16x8 b, f32x4 c) {
  return __builtin_amdgcn_mfma_f32_16x16x32_bf16(a, b, c, 0, 0, 0);
}
__device__ __forceinline__ void gload16(const unsigned short* src, unsigned short* dst) {
  __builtin_amdgcn_global_load_lds(
      (const __attribute__((address_space(1))) uint32_t*)src,
      (__attribute__((address_space(3))) uint32_t*)dst, 16, 0, 0);
}

// ---------------- fp32 -> bf16 convert ----------------
__global__ void cvt_kernel(const float* __restrict__ src, unsigned short* __restrict__ dst, int n4) {
  for (int i = blockIdx.x * blockDim.x + threadIdx.x; i < n4; i += gridDim.x * blockDim.x) {
    f32x4 v = ((const f32x4*)src)[i];
    u16x4 o;
    o[0] = f2bf(v[0]); o[1] = f2bf(v[1]); o[2] = f2bf(v[2]); o[3] = f2bf(v[3]);
    ((u16x4*)dst)[i] = o;
  }
}

// ---------------- GEMM: C[m][c] = sum_k A[m][k]*B[c][k] + bias[c] ----------------
// MODE 0: fp32 out C[m][NN].  MODE 1: bf16 out routed per column region:
//   c in [0,1024)    -> qo[m][c]
//   c in [1024,2048) -> kto[n][h][l][d]   (n=m&7, l=m>>3, h=(c-1024)/64, d=c%64)
//   c in [2048,3072) -> vo[m][c-2048]
template<int MODE>
__global__ __launch_bounds__(256) void gemm_bt(
    const unsigned short* __restrict__ A, const unsigned short* __restrict__ B,
    const float* __restrict__ bias, float* __restrict__ Cf,
    unsigned short* __restrict__ qo, unsigned short* __restrict__ kto,
    unsigned short* __restrict__ vo, int NN, int KDIM)
{
  __shared__ __align__(16) unsigned short a_lds[128 * 32];
  __shared__ __align__(16) unsigned short b_lds[128 * 32];

  const int nwg = gridDim.x;
  const int bid = blockIdx.x;
  const int q8 = nwg >> 3;
  const int swz = (bid & 7) * q8 + (bid >> 3);   // XCD-aware bijective remap
  const int brow = swz & 63;
  const int bcol = swz >> 6;

  const int tid = threadIdx.x;
  const int w = tid >> 6, lane = tid & 63;
  const int wr = w >> 1, wc = w & 1;
  const int lrow = lane & 15, g = lane >> 4;

  f32x4 acc[4][4];
#pragma unroll
  for (int i = 0; i < 4; ++i)
#pragma unroll
    for (int j = 0; j < 4; ++j) acc[i][j] = (f32x4){0.f, 0.f, 0.f, 0.f};

  const int r_in = lane >> 2;
  const int u = lane & 3;

  auto stage = [&](int kt) {
    const size_t kcol = (size_t)kt * 32 + u * 8;
    gload16(A + (size_t)(brow * 128 + 16 * w + r_in) * KDIM + kcol,       &a_lds[(16 * w) * 32]);
    gload16(A + (size_t)(brow * 128 + 16 * (w + 4) + r_in) * KDIM + kcol, &a_lds[(16 * (w + 4)) * 32]);
    gload16(B + (size_t)(bcol * 128 + 16 * w + r_in) * KDIM + kcol,       &b_lds[(16 * w) * 32]);
    gload16(B + (size_t)(bcol * 128 + 16 * (w + 4) + r_in) * KDIM + kcol, &b_lds[(16 * (w + 4)) * 32]);
  };

  const int KT = KDIM >> 5;
  stage(0);
  for (int kt = 0; kt < KT; ++kt) {
    __syncthreads();
    bf16x8 af[4], bfr[4];
#pragma unroll
    for (int mt = 0; mt < 4; ++mt)
      af[mt] = *(const bf16x8*)&a_lds[(wr * 64 + mt * 16 + lrow) * 32 + g * 8];
#pragma unroll
    for (int nt = 0; nt < 4; ++nt)
      bfr[nt] = *(const bf16x8*)&b_lds[(wc * 64 + nt * 16 + lrow) * 32 + g * 8];
#pragma unroll
    for (int mt = 0; mt < 4; ++mt)
#pragma unroll
      for (int nt = 0; nt < 4; ++nt)
        acc[mt][nt] = mfma16(af[mt], bfr[nt], acc[mt][nt]);
    __syncthreads();
    if (kt + 1 < KT) stage(kt + 1);
  }

#pragma unroll
  for (int nt = 0; nt < 4; ++nt) {
    const int c = bcol * 128 + wc * 64 + nt * 16 + lrow;
    const float bv = bias[c];
#pragma unroll
    for (int mt = 0; mt < 4; ++mt) {
      const int m0 = brow * 128 + wr * 64 + mt * 16 + g * 4;
#pragma unroll
      for (int j = 0; j < 4; ++j) {
        const float val = acc[mt][nt][j] + bv;
        const int m = m0 + j;
        if (MODE == 0) {
          Cf[(size_t)m * NN + c] = val;
        } else {
          const unsigned short b16 = f2bf(val);
          const int region = c >> 10, cl = c & 1023;
          if (region == 0)      qo[(size_t)m * EE + cl] = b16;
          else if (region == 2) vo[(size_t)m * EE + cl] = b16;
          else kto[((size_t)((m & 7) * HH + (cl >> 6)) * LL + (m >> 3)) * DD + (cl & 63)] = b16;
        }
      }
    }
  }
}

// ---------------- V transpose: v[m][1024] -> vt[n][h][d][s] ----------------
__global__ void transpose_v(const unsigned short* __restrict__ v, unsigned short* __restrict__ vt) {
  __shared__ __align__(16) unsigned short tile[64][68];
  const int b = blockIdx.x;                 // 2048
  const int lchunk = b & 15, h = (b >> 4) & 15, n = b >> 8;
  const int t = threadIdx.x;
  const int c4 = (t & 15) * 4, r = t >> 4;
#pragma unroll
  for (int p = 0; p < 4; ++p) {
    const int l = lchunk * 64 + p * 16 + r;
    u16x4 x = *(const u16x4*)&v[(size_t)(l * NB + n) * EE + h * DD + c4];
    *(u16x4*)&tile[p * 16 + r][c4] = x;
  }
  __syncthreads();
#pragma unroll
  for (int p = 0; p < 4; ++p) {
    const int d = p * 16 + r;
    u16x4 o;
#pragma unroll
    for (int i = 0; i < 4; ++i) o[i] = tile[c4 + i][d];
    *(u16x4*)&vt[((size_t)(n * HH + h) * DD + d) * LL + lchunk * 64 + c4] = o;
  }
}

// ---------------- flash attention (single pass, unnormalized accum) ----------------
// grid 2048 = n(8, XCD) x h(16) x ltile(16 of 64 rows); block 256 = 4 waves.
// Wave wv owns q-rows lt+wv*16..+15 and sweeps the full s range; waves are
// fully independent (no __syncthreads in this kernel). K/V read from global
// (L1/L2-resident 8KB chunks, 4 waves in lockstep). P repack via per-wave
// padded LDS (lgkm-ordered within wave).
__global__ __launch_bounds__(256) void attn_flash(
    const unsigned short* __restrict__ q,    // [m][1024] bf16
    const unsigned short* __restrict__ kt,   // [n][h][s][64]
    const unsigned short* __restrict__ vt,   // [n][h][64][1024]
    unsigned short* __restrict__ ctxo,       // [m][1024] bf16
    float* __restrict__ rinvb)               // [n][h][1024]
{
  __shared__ __align__(16) unsigned short pl[4][16][72];   // [wave][l][s-chunk], padded

  const int bid = blockIdx.x;
  const int n = bid & 7;
  const int rest = bid >> 3;
  const int h = rest >> 4;
  const int lt = (rest & 15) << 6;
  const int tid = threadIdx.x;
  const int wv = tid >> 6, lane = tid & 63;
  const int ll = lane & 15, g = lane >> 4;

  const int lrow = lt + wv * 16 + ll;
  const unsigned short* qp = q + ((size_t)lrow * NB + n) * EE + h * DD + g * 8;
  const bf16x8 qf0 = *(const bf16x8*)qp;
  const bf16x8 qf1 = *(const bf16x8*)(qp + 32);

  const unsigned short* kbase = kt + (size_t)(n * HH + h) * LL * DD + (size_t)ll * DD + g * 8;
  const unsigned short* vbase = vt + (size_t)(n * HH + h) * DD * LL;

  f32x4 ctx[4];
#pragma unroll
  for (int i = 0; i < 4; ++i) ctx[i] = (f32x4){0.f, 0.f, 0.f, 0.f};
  f32x4 sum4 = (f32x4){0.f, 0.f, 0.f, 0.f};

  for (int ch = 0; ch < 16; ++ch) {        // 64 s per chunk
    // ---- QK^T (swapped: lane ll owns q-row ll) + exp + stage P ----
#pragma unroll
    for (int t = 0; t < 4; ++t) {
      const unsigned short* kp = kbase + (size_t)(ch * 64 + t * 16) * DD;
      bf16x8 kf0 = *(const bf16x8*)kp;
      bf16x8 kf1 = *(const bf16x8*)(kp + 32);
      f32x4 sc = (f32x4){0.f, 0.f, 0.f, 0.f};
      sc = mfma16(kf0, qf0, sc);
      sc = mfma16(kf1, qf1, sc);
      f32x4 p;
      u16x4 pw;
#pragma unroll
      for (int j = 0; j < 4; ++j) {
        p[j] = __expf(sc[j] * 0.125f);
        pw[j] = f2bf(p[j]);
      }
      sum4 += p;
      *(u16x4*)&pl[wv][ll][t * 16 + g * 4] = pw;
    }
    // ---- PV: ctx_un += V^T . P^T (per-wave; lgkm ordering, no barrier) ----
    const bf16x8 pf0 = *(const bf16x8*)&pl[wv][ll][g * 8];
    const bf16x8 pf1 = *(const bf16x8*)&pl[wv][ll][32 + g * 8];
#pragma unroll
    for (int dt = 0; dt < 4; ++dt) {
      const unsigned short* vp = vbase + (size_t)(dt * 16 + ll) * LL + ch * 64 + g * 8;
      bf16x8 vf0 = *(const bf16x8*)vp;
      bf16x8 vf1 = *(const bf16x8*)(vp + 32);
      ctx[dt] = mfma16(vf0, pf0, ctx[dt]);
      ctx[dt] = mfma16(vf1, pf1, ctx[dt]);
    }
  }

  // ---- row sum -> rinv, normalize, store ----
  float s1 = sum4[0] + sum4[1] + sum4[2] + sum4[3];
  s1 += __shfl_xor(s1, 16);
  s1 += __shfl_xor(s1, 32);
  const float rinv = 1.0f / s1;
  if (lane < 16) rinvb[(size_t)(n * HH + h) * LL + lt + wv * 16 + lane] = rinv;

  unsigned short* cp = ctxo + ((size_t)lrow * NB + n) * EE + h * DD;
#pragma unroll
  for (int dt = 0; dt < 4; ++dt) {
    u16x4 o;
#pragma unroll
    for (int j = 0; j < 4; ++j) o[j] = f2bf(ctx[dt][j] * rinv);
    *(u16x4*)(cp + dt * 16 + g * 4) = o;
  }
}

// ---------------- head-mean attention output (recompute QK with known rinv) ----------------
// grid 1024 = n(8, XCD) x ltile(64 of 16 rows) x s-half(2); block 256 = 4 waves.
__global__ __launch_bounds__(256) void attn_mean(
    const unsigned short* __restrict__ q,    // [m][1024] bf16
    const unsigned short* __restrict__ kt,   // [n][h][s][64]
    const float* __restrict__ rinvb,         // [n][h][1024]
    float* __restrict__ attn_out)            // [n][1024][1024]
{
  const int bid = blockIdx.x;
  const int n = bid & 7;
  const int r = bid >> 3;                    // 0..127
  const int lt = (r & 63) << 4;
  const int sh = r >> 6;
  const int tid = threadIdx.x;
  const int wv = tid >> 6, lane = tid & 63;
  const int ll = lane & 15, g = lane >> 4;
  const int sb = sh * 512 + wv * 128;
  const int lrow = lt + ll;

  f32x4 acc[8];
#pragma unroll
  for (int i = 0; i < 8; ++i) acc[i] = (f32x4){0.f, 0.f, 0.f, 0.f};

  const unsigned short* qb2 = q + ((size_t)lrow * NB + n) * EE;

  for (int h = 0; h < HH; ++h) {
    const float rv = rinvb[(size_t)(n * HH + h) * LL + lrow];
    const unsigned short* qp = qb2 + h * DD + g * 8;
    const bf16x8 qf0 = *(const bf16x8*)qp;
    const bf16x8 qf1 = *(const bf16x8*)(qp + 32);
    const unsigned short* kp0 = kt + (size_t)(n * HH + h) * LL * DD + (size_t)(sb + ll) * DD + g * 8;
#pragma unroll
    for (int t = 0; t < 8; ++t) {
      const unsigned short* kp = kp0 + t * 16 * DD;
      bf16x8 kf0 = *(const bf16x8*)kp;
      bf16x8 kf1 = *(const bf16x8*)(kp + 32);
      f32x4 sc = (f32x4){0.f, 0.f, 0.f, 0.f};
      sc = mfma16(kf0, qf0, sc);
      sc = mfma16(kf1, qf1, sc);
#pragma unroll
      for (int j = 0; j < 4; ++j) acc[t][j] += __expf(sc[j] * 0.125f) * rv;
    }
  }

  float* ap = attn_out + ((size_t)n * LL + lrow) * LL + sb + g * 4;
#pragma unroll
  for (int t = 0; t < 8; ++t) {
    f32x4 o = acc[t] * 0.0625f;
    *(f32x4*)(ap + t * 16) = o;
  }
}

extern "C" void kernel_launch(void* const* d_in, const int* in_sizes, int n_in,
                              void* d_out, int out_size, void* d_ws, size_t ws_size,
                              hipStream_t stream) {
  const float* x   = (const float*)d_in[0];
  const float* win = (const float*)d_in[1];
  const float* bin = (const float*)d_in[2];
  const float* ow  = (const float*)d_in[3];
  const float* ob  = (const float*)d_in[4];
  float* out = (float*)d_out;

  const size_t need = ((size_t)MM * EE * 5 + (size_t)K3 * EE + (size_t)EE * EE) * 2
                    + (size_t)NB * HH * LL * 4;
  if (ws_size < need) return;

  unsigned short* ws  = (unsigned short*)d_ws;
  unsigned short* xb  = ws;                        // [8192][1024]  (reused as ctx)
  unsigned short* wb  = xb + (size_t)MM * EE;      // [3072][1024]
  unsigned short* owb = wb + (size_t)K3 * EE;      // [1024][1024]
  unsigned short* qb  = owb + (size_t)EE * EE;     // [8192][1024]
  unsigned short* ktb = qb + (size_t)MM * EE;      // [8][16][1024][64]
  unsigned short* vb  = ktb + (size_t)MM * EE;     // [8192][1024]
  unsigned short* vtb = vb + (size_t)MM * EE;      // [8][16][64][1024]
  float* rinvb = (float*)(vtb + (size_t)MM * EE);  // [8][16][1024]
  unsigned short* ctx = xb;

  cvt_kernel<<<2048, 256, 0, stream>>>(x, xb, (MM * EE) / 4);
  cvt_kernel<<<1024, 256, 0, stream>>>(win, wb, (K3 * EE) / 4);
  cvt_kernel<<<512, 256, 0, stream>>>(ow, owb, (EE * EE) / 4);
  gemm_bt<1><<<64 * (K3 / 128), 256, 0, stream>>>(xb, wb, bin, nullptr, qb, ktb, vb, K3, EE);
  transpose_v<<<2048, 256, 0, stream>>>(vb, vtb);
  attn_flash<<<2048, 256, 0, stream>>>(qb, ktb, vtb, ctx, rinvb);
  attn_mean<<<1024, 256, 0, stream>>>(qb, ktb, rinvb, out + (size_t)MM * EE);
  gemm_bt<0><<<64 * (EE / 128), 256, 0, stream>>>(ctx, owb, ob, out, nullptr, nullptr, nullptr, EE, EE);
}

// Round 5
// 402.716 us; speedup vs baseline: 1.3444x; 1.3444x over previous
//
#include <hip/hip_runtime.h>
#include <stdint.h>

#define LL 1024
#define NB 8
#define EE 1024
#define HH 16
#define DD 64
#define MM (LL*NB)      // 8192 rows (l*NB+n)
#define K3 (3*EE)       // 3072

typedef __attribute__((ext_vector_type(8))) short bf16x8;   // 8 bf16 in 4 VGPRs
typedef __attribute__((ext_vector_type(4))) float f32x4;
typedef __attribute__((ext_vector_type(4))) unsigned short u16x4;

__device__ __forceinline__ unsigned short f2bf(float f) {
  uint32_t u = __builtin_bit_cast(uint32_t, f);
  u += 0x7fffu + ((u >> 16) & 1u);           // RNE
  return (unsigned short)(u >> 16);
}
__device__ __forceinline__ f32x4 mfma16(bf16x8 a, bf16x8 b, f32x4 c) {
  return __builtin_amdgcn_mfma_f32_16x16x32_bf16(a, b, c, 0, 0, 0);
}
__device__ __forceinline__ void gload16(const unsigned short* src, unsigned short* dst) {
  __builtin_amdgcn_global_load_lds(
      (const __attribute__((address_space(1))) uint32_t*)src,
      (__attribute__((address_space(3))) uint32_t*)dst, 16, 0, 0);
}

// ---------------- fp32 -> bf16 convert ----------------
__global__ void cvt_kernel(const float* __restrict__ src, unsigned short* __restrict__ dst, int n4) {
  for (int i = blockIdx.x * blockDim.x + threadIdx.x; i < n4; i += gridDim.x * blockDim.x) {
    f32x4 v = ((const f32x4*)src)[i];
    u16x4 o;
    o[0] = f2bf(v[0]); o[1] = f2bf(v[1]); o[2] = f2bf(v[2]); o[3] = f2bf(v[3]);
    ((u16x4*)dst)[i] = o;
  }
}

// ---------------- GEMM: C[m][c] = sum_k A[m][k]*B[c][k] + bias[c] ----------------
// MODE 0: fp32 out C[m][NN].  MODE 1: bf16 out routed per column region:
//   c in [0,1024)    -> qo[m][c]
//   c in [1024,2048) -> kto[n][h][l][d]   (n=m&7, l=m>>3, h=(c-1024)/64, d=c%64)
//   c in [2048,3072) -> vo[m][c-2048]
template<int MODE>
__global__ __launch_bounds__(256) void gemm_bt(
    const unsigned short* __restrict__ A, const unsigned short* __restrict__ B,
    const float* __restrict__ bias, float* __restrict__ Cf,
    unsigned short* __restrict__ qo, unsigned short* __restrict__ kto,
    unsigned short* __restrict__ vo, int NN, int KDIM)
{
  __shared__ __align__(16) unsigned short a_lds[128 * 32];
  __shared__ __align__(16) unsigned short b_lds[128 * 32];

  const int nwg = gridDim.x;
  const int bid = blockIdx.x;
  const int q8 = nwg >> 3;
  const int swz = (bid & 7) * q8 + (bid >> 3);   // XCD-aware bijective remap
  const int brow = swz & 63;
  const int bcol = swz >> 6;

  const int tid = threadIdx.x;
  const int w = tid >> 6, lane = tid & 63;
  const int wr = w >> 1, wc = w & 1;
  const int lrow = lane & 15, g = lane >> 4;

  f32x4 acc[4][4];
#pragma unroll
  for (int i = 0; i < 4; ++i)
#pragma unroll
    for (int j = 0; j < 4; ++j) acc[i][j] = (f32x4){0.f, 0.f, 0.f, 0.f};

  const int r_in = lane >> 2;
  const int u = lane & 3;

  auto stage = [&](int kt) {
    const size_t kcol = (size_t)kt * 32 + u * 8;
    gload16(A + (size_t)(brow * 128 + 16 * w + r_in) * KDIM + kcol,       &a_lds[(16 * w) * 32]);
    gload16(A + (size_t)(brow * 128 + 16 * (w + 4) + r_in) * KDIM + kcol, &a_lds[(16 * (w + 4)) * 32]);
    gload16(B + (size_t)(bcol * 128 + 16 * w + r_in) * KDIM + kcol,       &b_lds[(16 * w) * 32]);
    gload16(B + (size_t)(bcol * 128 + 16 * (w + 4) + r_in) * KDIM + kcol, &b_lds[(16 * (w + 4)) * 32]);
  };

  const int KT = KDIM >> 5;
  stage(0);
  for (int kt = 0; kt < KT; ++kt) {
    __syncthreads();
    bf16x8 af[4], bfr[4];
#pragma unroll
    for (int mt = 0; mt < 4; ++mt)
      af[mt] = *(const bf16x8*)&a_lds[(wr * 64 + mt * 16 + lrow) * 32 + g * 8];
#pragma unroll
    for (int nt = 0; nt < 4; ++nt)
      bfr[nt] = *(const bf16x8*)&b_lds[(wc * 64 + nt * 16 + lrow) * 32 + g * 8];
#pragma unroll
    for (int mt = 0; mt < 4; ++mt)
#pragma unroll
      for (int nt = 0; nt < 4; ++nt)
        acc[mt][nt] = mfma16(af[mt], bfr[nt], acc[mt][nt]);
    __syncthreads();
    if (kt + 1 < KT) stage(kt + 1);
  }

#pragma unroll
  for (int nt = 0; nt < 4; ++nt) {
    const int c = bcol * 128 + wc * 64 + nt * 16 + lrow;
    const float bv = bias[c];
#pragma unroll
    for (int mt = 0; mt < 4; ++mt) {
      const int m0 = brow * 128 + wr * 64 + mt * 16 + g * 4;
#pragma unroll
      for (int j = 0; j < 4; ++j) {
        const float val = acc[mt][nt][j] + bv;
        const int m = m0 + j;
        if (MODE == 0) {
          Cf[(size_t)m * NN + c] = val;
        } else {
          const unsigned short b16 = f2bf(val);
          const int region = c >> 10, cl = c & 1023;
          if (region == 0)      qo[(size_t)m * EE + cl] = b16;
          else if (region == 2) vo[(size_t)m * EE + cl] = b16;
          else kto[((size_t)((m & 7) * HH + (cl >> 6)) * LL + (m >> 3)) * DD + (cl & 63)] = b16;
        }
      }
    }
  }
}

// ---------------- V transpose: v[m][1024] -> vt[n][h][d][s] ----------------
__global__ void transpose_v(const unsigned short* __restrict__ v, unsigned short* __restrict__ vt) {
  __shared__ __align__(16) unsigned short tile[64][68];
  const int b = blockIdx.x;                 // 2048
  const int lchunk = b & 15, h = (b >> 4) & 15, n = b >> 8;
  const int t = threadIdx.x;
  const int c4 = (t & 15) * 4, r = t >> 4;
#pragma unroll
  for (int p = 0; p < 4; ++p) {
    const int l = lchunk * 64 + p * 16 + r;
    u16x4 x = *(const u16x4*)&v[(size_t)(l * NB + n) * EE + h * DD + c4];
    *(u16x4*)&tile[p * 16 + r][c4] = x;
  }
  __syncthreads();
#pragma unroll
  for (int p = 0; p < 4; ++p) {
    const int d = p * 16 + r;
    u16x4 o;
#pragma unroll
    for (int i = 0; i < 4; ++i) o[i] = tile[c4 + i][d];
    *(u16x4*)&vt[((size_t)(n * HH + h) * DD + d) * LL + lchunk * 64 + c4] = o;
  }
}

// ---------------- flash attention (single pass, unnormalized accum) ----------------
// grid 2048 = n(8, XCD) x h(16) x ltile(16 of 64 rows); block 256 = 4 waves.
// K chunk (64 s x 64 d) staged to LDS via global_load_lds with source-side XOR
// swizzle (conflict-free ds_read_b128), double-buffered, 1 barrier per chunk.
// V prefetched to registers at chunk top. Numerics identical to round 4.
__global__ __launch_bounds__(256) void attn_flash(
    const unsigned short* __restrict__ q,    // [m][1024] bf16
    const unsigned short* __restrict__ kt,   // [n][h][s][64]
    const unsigned short* __restrict__ vt,   // [n][h][64][1024]
    unsigned short* __restrict__ ctxo,       // [m][1024] bf16
    float* __restrict__ rinvb)               // [n][h][1024]
{
  __shared__ __align__(16) unsigned short kc[2][64][64];   // [buf][s][d], XOR-swizzled
  __shared__ __align__(16) unsigned short pl[4][16][72];   // [wave][l][s-chunk], padded

  const int bid = blockIdx.x;
  const int n = bid & 7;
  const int rest = bid >> 3;
  const int h = rest >> 4;
  const int lt = (rest & 15) << 6;
  const int tid = threadIdx.x;
  const int wv = tid >> 6, lane = tid & 63;
  const int ll = lane & 15, g = lane >> 4;
  const int a3 = ll & 7;

  const int lrow = lt + wv * 16 + ll;
  const unsigned short* qp = q + ((size_t)lrow * NB + n) * EE + h * DD + g * 8;
  const bf16x8 qf0 = *(const bf16x8*)qp;
  const bf16x8 qf1 = *(const bf16x8*)(qp + 32);

  const unsigned short* kslab = kt + (size_t)(n * HH + h) * LL * DD;
  const unsigned short* vbase = vt + (size_t)(n * HH + h) * DD * LL;

  // staging swizzle: lane lam writes LDS row r8=lam/8, unit lam%8; source unit
  // must be (lam%8)^(row&7) so that LDS[row][u'] = G[row][u' ^ (row&7)]
  const int r8 = lane >> 3;
  const int c16 = (lane & 7) ^ r8;

  // swizzled read offsets (bytes within a [64][64-short] tile, 128B rows)
  const int kof0 = ll * 128 + ((g ^ a3) << 4);        // units 0..3  (k 0..31)
  const int kof1 = ll * 128 + (((4 + g) ^ a3) << 4);  // units 4..7  (k 32..63)

  auto stageK = [&](int buf, int ch) {
    unsigned short* kd = &kc[buf][wv * 16][0];                 // wave-uniform dest
    const unsigned short* src = kslab + (size_t)(ch * 64 + wv * 16) * DD;
    gload16(src + (size_t)r8 * DD + c16 * 8,       kd);
    gload16(src + (size_t)(8 + r8) * DD + c16 * 8, kd + 8 * 64);
  };

  f32x4 ctx[4];
#pragma unroll
  for (int i = 0; i < 4; ++i) ctx[i] = (f32x4){0.f, 0.f, 0.f, 0.f};
  f32x4 sum4 = (f32x4){0.f, 0.f, 0.f, 0.f};

  stageK(0, 0);
  for (int ch = 0; ch < 16; ++ch) {        // 64 s per chunk
    __syncthreads();                       // stage drained (vmcnt0) + prev reads done
    const int buf = ch & 1;
    const char* kb = (const char*)&kc[buf][0][0];

    // ---- prefetch V fragments for this chunk (independent of K/P chain) ----
    bf16x8 vf0[4], vf1[4];
#pragma unroll
    for (int dt = 0; dt < 4; ++dt) {
      const unsigned short* vp = vbase + (size_t)(dt * 16 + ll) * LL + ch * 64 + g * 8;
      vf0[dt] = *(const bf16x8*)vp;
      vf1[dt] = *(const bf16x8*)(vp + 32);
    }

    // ---- QK^T (swapped: lane ll owns q-row ll) + exp + stage P ----
#pragma unroll
    for (int t = 0; t < 4; ++t) {
      bf16x8 kf0 = *(const bf16x8*)(kb + t * 2048 + kof0);
      bf16x8 kf1 = *(const bf16x8*)(kb + t * 2048 + kof1);
      f32x4 sc = (f32x4){0.f, 0.f, 0.f, 0.f};
      sc = mfma16(kf0, qf0, sc);
      sc = mfma16(kf1, qf1, sc);
      f32x4 p;
      u16x4 pw;
#pragma unroll
      for (int j = 0; j < 4; ++j) {
        p[j] = __expf(sc[j] * 0.125f);
        pw[j] = f2bf(p[j]);
      }
      sum4 += p;
      *(u16x4*)&pl[wv][ll][t * 16 + g * 4] = pw;
    }
    // ---- PV: ctx_un += V^T . P^T (per-wave; lgkm ordering, no barrier) ----
    const bf16x8 pf0 = *(const bf16x8*)&pl[wv][ll][g * 8];
    const bf16x8 pf1 = *(const bf16x8*)&pl[wv][ll][32 + g * 8];
#pragma unroll
    for (int dt = 0; dt < 4; ++dt) {
      ctx[dt] = mfma16(vf0[dt], pf0, ctx[dt]);
      ctx[dt] = mfma16(vf1[dt], pf1, ctx[dt]);
    }
    if (ch < 15) stageK(buf ^ 1, ch + 1);  // safe: issued after this iter's barrier
  }

  // ---- row sum -> rinv, normalize, store ----
  float s1 = sum4[0] + sum4[1] + sum4[2] + sum4[3];
  s1 += __shfl_xor(s1, 16);
  s1 += __shfl_xor(s1, 32);
  const float rinv = 1.0f / s1;
  if (lane < 16) rinvb[(size_t)(n * HH + h) * LL + lt + wv * 16 + lane] = rinv;

  unsigned short* cp = ctxo + ((size_t)lrow * NB + n) * EE + h * DD;
#pragma unroll
  for (int dt = 0; dt < 4; ++dt) {
    u16x4 o;
#pragma unroll
    for (int j = 0; j < 4; ++j) o[j] = f2bf(ctx[dt][j] * rinv);
    *(u16x4*)(cp + dt * 16 + g * 4) = o;
  }
}

// ---------------- head-mean attention output (recompute QK with known rinv) ----------------
// grid 1024 = n(8, XCD) x ltile(64 of 16 rows) x s-half(2); block 256 = 4 waves.
// t outer, h fully-unrolled inner: 16 independent load->MFMA->exp chains in flight.
__global__ __launch_bounds__(256) void attn_mean(
    const unsigned short* __restrict__ q,    // [m][1024] bf16
    const unsigned short* __restrict__ kt,   // [n][h][s][64]
    const float* __restrict__ rinvb,         // [n][h][1024]
    float* __restrict__ attn_out)            // [n][1024][1024]
{
  const int bid = blockIdx.x;
  const int n = bid & 7;
  const int r = bid >> 3;                    // 0..127
  const int lt = (r & 63) << 4;
  const int sh = r >> 6;
  const int tid = threadIdx.x;
  const int wv = tid >> 6, lane = tid & 63;
  const int ll = lane & 15, g = lane >> 4;
  const int sb = sh * 512 + wv * 128;
  const int lrow = lt + ll;

  float rv[16];
#pragma unroll
  for (int h = 0; h < HH; ++h) rv[h] = rinvb[(size_t)(n * HH + h) * LL + lrow];

  const unsigned short* qb2 = q + ((size_t)lrow * NB + n) * EE + g * 8;
  const unsigned short* kb2 = kt + (size_t)n * HH * LL * DD + (size_t)(sb + ll) * DD + g * 8;
  float* ap = attn_out + ((size_t)n * LL + lrow) * LL + sb + g * 4;

  for (int t = 0; t < 8; ++t) {
    f32x4 a = (f32x4){0.f, 0.f, 0.f, 0.f};
#pragma unroll
    for (int h = 0; h < HH; ++h) {
      const unsigned short* qp = qb2 + h * DD;
      bf16x8 qf0 = *(const bf16x8*)qp;
      bf16x8 qf1 = *(const bf16x8*)(qp + 32);
      const unsigned short* kp = kb2 + (size_t)h * LL * DD + t * 16 * DD;
      bf16x8 kf0 = *(const bf16x8*)kp;
      bf16x8 kf1 = *(const bf16x8*)(kp + 32);
      f32x4 sc = (f32x4){0.f, 0.f, 0.f, 0.f};
      sc = mfma16(kf0, qf0, sc);
      sc = mfma16(kf1, qf1, sc);
#pragma unroll
      for (int j = 0; j < 4; ++j) a[j] += __expf(sc[j] * 0.125f) * rv[h];
    }
    *(f32x4*)(ap + t * 16) = a * 0.0625f;
  }
}

extern "C" void kernel_launch(void* const* d_in, const int* in_sizes, int n_in,
                              void* d_out, int out_size, void* d_ws, size_t ws_size,
                              hipStream_t stream) {
  const float* x   = (const float*)d_in[0];
  const float* win = (const float*)d_in[1];
  const float* bin = (const float*)d_in[2];
  const float* ow  = (const float*)d_in[3];
  const float* ob  = (const float*)d_in[4];
  float* out = (float*)d_out;

  const size_t need = ((size_t)MM * EE * 5 + (size_t)K3 * EE + (size_t)EE * EE) * 2
                    + (size_t)NB * HH * LL * 4;
  if (ws_size < need) return;

  unsigned short* ws  = (unsigned short*)d_ws;
  unsigned short* xb  = ws;                        // [8192][1024]  (reused as ctx)
  unsigned short* wb  = xb + (size_t)MM * EE;      // [3072][1024]
  unsigned short* owb = wb + (size_t)K3 * EE;      // [1024][1024]
  unsigned short* qb  = owb + (size_t)EE * EE;     // [8192][1024]
  unsigned short* ktb = qb + (size_t)MM * EE;      // [8][16][1024][64]
  unsigned short* vb  = ktb + (size_t)MM * EE;     // [8192][1024]
  unsigned short* vtb = vb + (size_t)MM * EE;      // [8][16][64][1024]
  float* rinvb = (float*)(vtb + (size_t)MM * EE);  // [8][16][1024]
  unsigned short* ctx = xb;

  cvt_kernel<<<2048, 256, 0, stream>>>(x, xb, (MM * EE) / 4);
  cvt_kernel<<<1024, 256, 0, stream>>>(win, wb, (K3 * EE) / 4);
  cvt_kernel<<<512, 256, 0, stream>>>(ow, owb, (EE * EE) / 4);
  gemm_bt<1><<<64 * (K3 / 128), 256, 0, stream>>>(xb, wb, bin, nullptr, qb, ktb, vb, K3, EE);
  transpose_v<<<2048, 256, 0, stream>>>(vb, vtb);
  attn_flash<<<2048, 256, 0, stream>>>(qb, ktb, vtb, ctx, rinvb);
  attn_mean<<<1024, 256, 0, stream>>>(qb, ktb, rinvb, out + (size_t)MM * EE);
  gemm_bt<0><<<64 * (EE / 128), 256, 0, stream>>>(ctx, owb, ob, out, nullptr, nullptr, nullptr, EE, EE);
}

// Round 6
// 266.340 us; speedup vs baseline: 2.0328x; 1.5120x over previous
//
#include <hip/hip_runtime.h>
#include <stdint.h>

#define LL 1024
#define NB 8
#define EE 1024
#define HH 16
#define DD 64
#define MM (LL*NB)      // 8192 rows (l*NB+n)
#define K3 (3*EE)       // 3072

typedef __attribute__((ext_vector_type(8))) short bf16x8;   // 8 bf16 in 4 VGPRs
typedef __attribute__((ext_vector_type(4))) float f32x4;
typedef __attribute__((ext_vector_type(4))) unsigned short u16x4;

__device__ __forceinline__ unsigned short f2bf(float f) {
  uint32_t u = __builtin_bit_cast(uint32_t, f);
  u += 0x7fffu + ((u >> 16) & 1u);           // RNE
  return (unsigned short)(u >> 16);
}
// HW RNE pack: dst = [bf16(hi)|bf16(lo)] — bit-identical to f2bf pairs
__device__ __forceinline__ uint32_t cvtpk(float lo, float hi) {
  uint32_t d;
  asm volatile("v_cvt_pk_bf16_f32 %0, %1, %2" : "=v"(d) : "v"(lo), "v"(hi));
  return d;
}
__device__ __forceinline__ f32x4 mfma16(bf16x8 a, bf16x8 b, f32x4 c) {
  return __builtin_amdgcn_mfma_f32_16x16x32_bf16(a, b, c, 0, 0, 0);
}
__device__ __forceinline__ void gload16(const unsigned short* src, unsigned short* dst) {
  __builtin_amdgcn_global_load_lds(
      (const __attribute__((address_space(1))) uint32_t*)src,
      (__attribute__((address_space(3))) uint32_t*)dst, 16, 0, 0);
}

// ---------------- fp32 -> bf16 convert ----------------
__global__ void cvt_kernel(const float* __restrict__ src, unsigned short* __restrict__ dst, int n4) {
  for (int i = blockIdx.x * blockDim.x + threadIdx.x; i < n4; i += gridDim.x * blockDim.x) {
    f32x4 v = ((const f32x4*)src)[i];
    u16x4 o;
    o[0] = f2bf(v[0]); o[1] = f2bf(v[1]); o[2] = f2bf(v[2]); o[3] = f2bf(v[3]);
    ((u16x4*)dst)[i] = o;
  }
}

// ---------------- GEMM: C[m][c] = sum_k A[m][k]*B[c][k] + bias[c] ----------------
// MODE 0: fp32 out C[m][NN].  MODE 1: bf16 out routed per column region:
//   c in [0,1024)    -> qo[m][c]  (pre-scaled by 0.125 — exact, power of 2)
//   c in [1024,2048) -> kto[n][h][l][d]
//   c in [2048,3072) -> vo[m][c-2048]
template<int MODE>
__global__ __launch_bounds__(256) void gemm_bt(
    const unsigned short* __restrict__ A, const unsigned short* __restrict__ B,
    const float* __restrict__ bias, float* __restrict__ Cf,
    unsigned short* __restrict__ qo, unsigned short* __restrict__ kto,
    unsigned short* __restrict__ vo, int NN, int KDIM)
{
  __shared__ __align__(16) unsigned short a_lds[128 * 32];
  __shared__ __align__(16) unsigned short b_lds[128 * 32];

  const int nwg = gridDim.x;
  const int bid = blockIdx.x;
  const int q8 = nwg >> 3;
  const int swz = (bid & 7) * q8 + (bid >> 3);   // XCD-aware bijective remap
  const int brow = swz & 63;
  const int bcol = swz >> 6;

  const int tid = threadIdx.x;
  const int w = tid >> 6, lane = tid & 63;
  const int wr = w >> 1, wc = w & 1;
  const int lrow = lane & 15, g = lane >> 4;

  f32x4 acc[4][4];
#pragma unroll
  for (int i = 0; i < 4; ++i)
#pragma unroll
    for (int j = 0; j < 4; ++j) acc[i][j] = (f32x4){0.f, 0.f, 0.f, 0.f};

  const int r_in = lane >> 2;
  const int u = lane & 3;

  auto stage = [&](int kt) {
    const size_t kcol = (size_t)kt * 32 + u * 8;
    gload16(A + (size_t)(brow * 128 + 16 * w + r_in) * KDIM + kcol,       &a_lds[(16 * w) * 32]);
    gload16(A + (size_t)(brow * 128 + 16 * (w + 4) + r_in) * KDIM + kcol, &a_lds[(16 * (w + 4)) * 32]);
    gload16(B + (size_t)(bcol * 128 + 16 * w + r_in) * KDIM + kcol,       &b_lds[(16 * w) * 32]);
    gload16(B + (size_t)(bcol * 128 + 16 * (w + 4) + r_in) * KDIM + kcol, &b_lds[(16 * (w + 4)) * 32]);
  };

  const int KT = KDIM >> 5;
  stage(0);
  for (int kt = 0; kt < KT; ++kt) {
    __syncthreads();
    bf16x8 af[4], bfr[4];
#pragma unroll
    for (int mt = 0; mt < 4; ++mt)
      af[mt] = *(const bf16x8*)&a_lds[(wr * 64 + mt * 16 + lrow) * 32 + g * 8];
#pragma unroll
    for (int nt = 0; nt < 4; ++nt)
      bfr[nt] = *(const bf16x8*)&b_lds[(wc * 64 + nt * 16 + lrow) * 32 + g * 8];
#pragma unroll
    for (int mt = 0; mt < 4; ++mt)
#pragma unroll
      for (int nt = 0; nt < 4; ++nt)
        acc[mt][nt] = mfma16(af[mt], bfr[nt], acc[mt][nt]);
    __syncthreads();
    if (kt + 1 < KT) stage(kt + 1);
  }

#pragma unroll
  for (int nt = 0; nt < 4; ++nt) {
    const int c = bcol * 128 + wc * 64 + nt * 16 + lrow;
    const float bv = bias[c];
#pragma unroll
    for (int mt = 0; mt < 4; ++mt) {
      const int m0 = brow * 128 + wr * 64 + mt * 16 + g * 4;
#pragma unroll
      for (int j = 0; j < 4; ++j) {
        const float val = acc[mt][nt][j] + bv;
        const int m = m0 + j;
        if (MODE == 0) {
          Cf[(size_t)m * NN + c] = val;
        } else {
          const int region = c >> 10, cl = c & 1023;
          if (region == 0)      qo[(size_t)m * EE + cl] = f2bf(val * 0.125f);
          else if (region == 2) vo[(size_t)m * EE + cl] = f2bf(val);
          else kto[((size_t)((m & 7) * HH + (cl >> 6)) * LL + (m >> 3)) * DD + (cl & 63)] = f2bf(val);
        }
      }
    }
  }
}

// ---------------- V transpose: v[m][1024] -> vt[n][h][d][s] ----------------
__global__ void transpose_v(const unsigned short* __restrict__ v, unsigned short* __restrict__ vt) {
  __shared__ __align__(16) unsigned short tile[64][68];
  const int b = blockIdx.x;                 // 2048
  const int lchunk = b & 15, h = (b >> 4) & 15, n = b >> 8;
  const int t = threadIdx.x;
  const int c4 = (t & 15) * 4, r = t >> 4;
#pragma unroll
  for (int p = 0; p < 4; ++p) {
    const int l = lchunk * 64 + p * 16 + r;
    u16x4 x = *(const u16x4*)&v[(size_t)(l * NB + n) * EE + h * DD + c4];
    *(u16x4*)&tile[p * 16 + r][c4] = x;
  }
  __syncthreads();
#pragma unroll
  for (int p = 0; p < 4; ++p) {
    const int d = p * 16 + r;
    u16x4 o;
#pragma unroll
    for (int i = 0; i < 4; ++i) o[i] = tile[c4 + i][d];
    *(u16x4*)&vt[((size_t)(n * HH + h) * DD + d) * LL + lchunk * 64 + c4] = o;
  }
}

// ---------------- flash attention (single pass, unnormalized accum) ----------------
// grid 1024 = n(8, XCD) x h(16) x ltile(8 of 128 rows); block 256 = 4 waves.
// Each wave owns TWO 16-row q-tiles (ltA = lt+wv*16, ltB = lt+64+wv*16): two
// independent QK->exp->PV chains for ILP; V fragments shared between tiles.
// K chunk staged to LDS (XOR-swizzled source), double-buffered, 1 barrier/chunk.
__global__ __launch_bounds__(256) void attn_flash(
    const unsigned short* __restrict__ q,    // [m][1024] bf16, pre-scaled by 0.125
    const unsigned short* __restrict__ kt,   // [n][h][s][64]
    const unsigned short* __restrict__ vt,   // [n][h][64][1024]
    unsigned short* __restrict__ ctxo,       // [m][1024] bf16
    float* __restrict__ rinvb)               // [n][h][1024]
{
  __shared__ __align__(16) unsigned short kc[2][64][64];      // [buf][s][d], swizzled
  __shared__ __align__(16) unsigned short pl[4][2][16][72];   // [wave][tile][l][s]

  const int bid = blockIdx.x;
  const int n = bid & 7;
  const int rest = bid >> 3;        // 0..127
  const int h = rest >> 3;          // 0..15
  const int lt = (rest & 7) << 7;   // 0..896 step 128
  const int tid = threadIdx.x;
  const int wv = tid >> 6, lane = tid & 63;
  const int ll = lane & 15, g = lane >> 4;
  const int a3 = ll & 7;

  const int ltA = lt + wv * 16 + ll;
  const int ltB = lt + 64 + wv * 16 + ll;
  const unsigned short* qpA = q + ((size_t)ltA * NB + n) * EE + h * DD + g * 8;
  const unsigned short* qpB = q + ((size_t)ltB * NB + n) * EE + h * DD + g * 8;
  const bf16x8 qfA0 = *(const bf16x8*)qpA;
  const bf16x8 qfA1 = *(const bf16x8*)(qpA + 32);
  const bf16x8 qfB0 = *(const bf16x8*)qpB;
  const bf16x8 qfB1 = *(const bf16x8*)(qpB + 32);

  const unsigned short* kslab = kt + (size_t)(n * HH + h) * LL * DD;
  const unsigned short* vbase = vt + (size_t)(n * HH + h) * DD * LL;

  // staging: lane lam -> LDS row lam/8, unit lam%8; source unit (lam%8)^(row&7)
  const int r8 = lane >> 3;
  const int c16 = (lane & 7) ^ r8;
  // swizzled read offsets (bytes; 128B rows): row&7 == ll&7 == a3
  const int kof0 = ll * 128 + ((g ^ a3) << 4);        // k units 0..3
  const int kof1 = ll * 128 + (((4 + g) ^ a3) << 4);  // k units 4..7

  auto stageK = [&](int buf, int ch) {
    unsigned short* kd = &kc[buf][wv * 16][0];
    const unsigned short* src = kslab + (size_t)(ch * 64 + wv * 16) * DD;
    gload16(src + (size_t)r8 * DD + c16 * 8,       kd);
    gload16(src + (size_t)(8 + r8) * DD + c16 * 8, kd + 8 * 64);
  };

  f32x4 ctxA[4], ctxB[4];
#pragma unroll
  for (int i = 0; i < 4; ++i) { ctxA[i] = (f32x4){0.f,0.f,0.f,0.f}; ctxB[i] = (f32x4){0.f,0.f,0.f,0.f}; }
  f32x4 sumA = (f32x4){0.f,0.f,0.f,0.f}, sumB = (f32x4){0.f,0.f,0.f,0.f};

  char* plbA = (char*)&pl[wv][0][0][0];
  char* plbB = (char*)&pl[wv][1][0][0];

  stageK(0, 0);
  for (int ch = 0; ch < 16; ++ch) {
    __syncthreads();
    const int buf = ch & 1;
    const char* kb = (const char*)&kc[buf][0][0];

    // prefetch V fragments (shared by both tiles)
    bf16x8 vf0[4], vf1[4];
#pragma unroll
    for (int dt = 0; dt < 4; ++dt) {
      const unsigned short* vp = vbase + (size_t)(dt * 16 + ll) * LL + ch * 64 + g * 8;
      vf0[dt] = *(const bf16x8*)vp;
      vf1[dt] = *(const bf16x8*)(vp + 32);
    }

    // QK^T + exp + P stage, two tiles interleaved
#pragma unroll
    for (int t = 0; t < 4; ++t) {
      bf16x8 kf0 = *(const bf16x8*)(kb + t * 2048 + kof0);
      bf16x8 kf1 = *(const bf16x8*)(kb + t * 2048 + kof1);
      f32x4 scA = (f32x4){0.f,0.f,0.f,0.f};
      f32x4 scB = (f32x4){0.f,0.f,0.f,0.f};
      scA = mfma16(kf0, qfA0, scA); scA = mfma16(kf1, qfA1, scA);
      scB = mfma16(kf0, qfB0, scB); scB = mfma16(kf1, qfB1, scB);
      f32x4 pA, pB;
#pragma unroll
      for (int j = 0; j < 4; ++j) { pA[j] = __expf(scA[j]); pB[j] = __expf(scB[j]); }
      sumA += pA; sumB += pB;
      uint2 wA; wA.x = cvtpk(pA[0], pA[1]); wA.y = cvtpk(pA[2], pA[3]);
      uint2 wB; wB.x = cvtpk(pB[0], pB[1]); wB.y = cvtpk(pB[2], pB[3]);
      *(uint2*)(plbA + ll * 144 + (t * 16 + g * 4) * 2) = wA;
      *(uint2*)(plbB + ll * 144 + (t * 16 + g * 4) * 2) = wB;
    }
    // PV for both tiles
    const bf16x8 pfA0 = *(const bf16x8*)(plbA + ll * 144 + g * 16);
    const bf16x8 pfA1 = *(const bf16x8*)(plbA + ll * 144 + 64 + g * 16);
    const bf16x8 pfB0 = *(const bf16x8*)(plbB + ll * 144 + g * 16);
    const bf16x8 pfB1 = *(const bf16x8*)(plbB + ll * 144 + 64 + g * 16);
#pragma unroll
    for (int dt = 0; dt < 4; ++dt) {
      ctxA[dt] = mfma16(vf0[dt], pfA0, ctxA[dt]);
      ctxA[dt] = mfma16(vf1[dt], pfA1, ctxA[dt]);
      ctxB[dt] = mfma16(vf0[dt], pfB0, ctxB[dt]);
      ctxB[dt] = mfma16(vf1[dt], pfB1, ctxB[dt]);
    }
    if (ch < 15) stageK(buf ^ 1, ch + 1);
  }

  // row sums -> rinv, normalize, store (per tile)
  float sA = sumA[0] + sumA[1] + sumA[2] + sumA[3];
  sA += __shfl_xor(sA, 16); sA += __shfl_xor(sA, 32);
  float sB = sumB[0] + sumB[1] + sumB[2] + sumB[3];
  sB += __shfl_xor(sB, 16); sB += __shfl_xor(sB, 32);
  const float rinvA = 1.0f / sA, rinvB = 1.0f / sB;
  if (lane < 16) {
    rinvb[(size_t)(n * HH + h) * LL + lt + wv * 16 + lane] = rinvA;
    rinvb[(size_t)(n * HH + h) * LL + lt + 64 + wv * 16 + lane] = rinvB;
  }

  unsigned short* cpA = ctxo + ((size_t)ltA * NB + n) * EE + h * DD;
  unsigned short* cpB = ctxo + ((size_t)ltB * NB + n) * EE + h * DD;
#pragma unroll
  for (int dt = 0; dt < 4; ++dt) {
    uint2 oA; oA.x = cvtpk(ctxA[dt][0]*rinvA, ctxA[dt][1]*rinvA);
    oA.y = cvtpk(ctxA[dt][2]*rinvA, ctxA[dt][3]*rinvA);
    uint2 oB; oB.x = cvtpk(ctxB[dt][0]*rinvB, ctxB[dt][1]*rinvB);
    oB.y = cvtpk(ctxB[dt][2]*rinvB, ctxB[dt][3]*rinvB);
    *(uint2*)(cpA + dt * 16 + g * 4) = oA;
    *(uint2*)(cpB + dt * 16 + g * 4) = oB;
  }
}

// ---------------- head-mean attention output (recompute QK with known rinv) ----------------
// grid 1024 = n(8, XCD) x [sh(8 of 128 s) x lt(16 of 64 rows)]; block 256 = 4 waves.
// K window [128 s][64 d] staged to LDS dbuf (XOR swizzle), shared by all 4 waves;
// wave wv owns q-rows lt+wv*16..+15; 8 independent t-chains; 1 barrier per head.
__global__ __launch_bounds__(256) void attn_mean(
    const unsigned short* __restrict__ q,    // [m][1024] bf16, pre-scaled by 0.125
    const unsigned short* __restrict__ kt,   // [n][h][s][64]
    const float* __restrict__ rinvb,         // [n][h][1024]
    float* __restrict__ attn_out)            // [n][1024][1024]
{
  __shared__ __align__(16) unsigned short kc[2][128][64];  // 32KB, swizzled

  const int bid = blockIdx.x;
  const int n = bid & 7;
  const int r = bid >> 3;                    // 0..127
  const int sh = r & 7;
  const int lt = (r >> 3) << 6;
  const int tid = threadIdx.x;
  const int wv = tid >> 6, lane = tid & 63;
  const int ll = lane & 15, g = lane >> 4;
  const int a3 = ll & 7;
  const int sb = sh << 7;
  const int lrow = lt + wv * 16 + ll;

  const int r8 = lane >> 3;
  const int c16 = (lane & 7) ^ r8;
  const int kof0 = ll * 128 + ((g ^ a3) << 4);
  const int kof1 = ll * 128 + (((4 + g) ^ a3) << 4);

  const unsigned short* kwin = kt + (size_t)n * HH * LL * DD + (size_t)sb * DD;

  auto stage = [&](int buf, int h) {
    unsigned short* kd = &kc[buf][wv * 32][0];
    const unsigned short* src = kwin + (size_t)h * LL * DD + (size_t)(wv * 32) * DD;
#pragma unroll
    for (int i = 0; i < 4; ++i)
      gload16(src + (size_t)(i * 8 + r8) * DD + c16 * 8, kd + i * 8 * 64);
  };

  float rv[16];
#pragma unroll
  for (int h = 0; h < HH; ++h) rv[h] = rinvb[(size_t)(n * HH + h) * LL + lrow];

  const unsigned short* qb2 = q + ((size_t)lrow * NB + n) * EE + g * 8;

  f32x4 acc[8];
#pragma unroll
  for (int i = 0; i < 8; ++i) acc[i] = (f32x4){0.f, 0.f, 0.f, 0.f};

  stage(0, 0);
  for (int h = 0; h < HH; ++h) {
    __syncthreads();
    const char* kb = (const char*)&kc[h & 1][0][0];
    const unsigned short* qp = qb2 + h * DD;
    const bf16x8 qf0 = *(const bf16x8*)qp;
    const bf16x8 qf1 = *(const bf16x8*)(qp + 32);
    const float rvh = rv[h];
#pragma unroll
    for (int t = 0; t < 8; ++t) {
      bf16x8 kf0 = *(const bf16x8*)(kb + t * 2048 + kof0);
      bf16x8 kf1 = *(const bf16x8*)(kb + t * 2048 + kof1);
      f32x4 sc = (f32x4){0.f, 0.f, 0.f, 0.f};
      sc = mfma16(kf0, qf0, sc);
      sc = mfma16(kf1, qf1, sc);
#pragma unroll
      for (int j = 0; j < 4; ++j) acc[t][j] += __expf(sc[j]) * rvh;
    }
    if (h + 1 < HH) stage((h + 1) & 1, h + 1);
  }

  float* ap = attn_out + ((size_t)n * LL + lrow) * LL + sb + g * 4;
#pragma unroll
  for (int t = 0; t < 8; ++t) *(f32x4*)(ap + t * 16) = acc[t] * 0.0625f;
}

extern "C" void kernel_launch(void* const* d_in, const int* in_sizes, int n_in,
                              void* d_out, int out_size, void* d_ws, size_t ws_size,
                              hipStream_t stream) {
  const float* x   = (const float*)d_in[0];
  const float* win = (const float*)d_in[1];
  const float* bin = (const float*)d_in[2];
  const float* ow  = (const float*)d_in[3];
  const float* ob  = (const float*)d_in[4];
  float* out = (float*)d_out;

  const size_t need = ((size_t)MM * EE * 5 + (size_t)K3 * EE + (size_t)EE * EE) * 2
                    + (size_t)NB * HH * LL * 4;
  if (ws_size < need) return;

  unsigned short* ws  = (unsigned short*)d_ws;
  unsigned short* xb  = ws;                        // [8192][1024]  (reused as ctx)
  unsigned short* wb  = xb + (size_t)MM * EE;      // [3072][1024]
  unsigned short* owb = wb + (size_t)K3 * EE;      // [1024][1024]
  unsigned short* qb  = owb + (size_t)EE * EE;     // [8192][1024]
  unsigned short* ktb = qb + (size_t)MM * EE;      // [8][16][1024][64]
  unsigned short* vb  = ktb + (size_t)MM * EE;     // [8192][1024]
  unsigned short* vtb = vb + (size_t)MM * EE;      // [8][16][64][1024]
  float* rinvb = (float*)(vtb + (size_t)MM * EE);  // [8][16][1024]
  unsigned short* ctx = xb;

  cvt_kernel<<<2048, 256, 0, stream>>>(x, xb, (MM * EE) / 4);
  cvt_kernel<<<1024, 256, 0, stream>>>(win, wb, (K3 * EE) / 4);
  cvt_kernel<<<512, 256, 0, stream>>>(ow, owb, (EE * EE) / 4);
  gemm_bt<1><<<64 * (K3 / 128), 256, 0, stream>>>(xb, wb, bin, nullptr, qb, ktb, vb, K3, EE);
  transpose_v<<<2048, 256, 0, stream>>>(vb, vtb);
  attn_flash<<<1024, 256, 0, stream>>>(qb, ktb, vtb, ctx, rinvb);
  attn_mean<<<1024, 256, 0, stream>>>(qb, ktb, rinvb, out + (size_t)MM * EE);
  gemm_bt<0><<<64 * (EE / 128), 256, 0, stream>>>(ctx, owb, ob, out, nullptr, nullptr, nullptr, EE, EE);
}

// Round 7
// 240.938 us; speedup vs baseline: 2.2471x; 1.1054x over previous
//
#include <hip/hip_runtime.h>
#include <stdint.h>

#define LL 1024
#define NB 8
#define EE 1024
#define HH 16
#define DD 64
#define MM (LL*NB)      // 8192 rows (l*NB+n)
#define K3 (3*EE)       // 3072

typedef __attribute__((ext_vector_type(8))) short bf16x8;   // 8 bf16 in 4 VGPRs
typedef __attribute__((ext_vector_type(4))) float f32x4;
typedef __attribute__((ext_vector_type(4))) unsigned short u16x4;
typedef __attribute__((ext_vector_type(8))) unsigned short u16x8;

__device__ __forceinline__ unsigned short f2bf(float f) {
  uint32_t u = __builtin_bit_cast(uint32_t, f);
  u += 0x7fffu + ((u >> 16) & 1u);           // RNE
  return (unsigned short)(u >> 16);
}
// HW RNE pack: dst = [bf16(hi)|bf16(lo)] — bit-identical to f2bf pairs
__device__ __forceinline__ uint32_t cvtpk(float lo, float hi) {
  uint32_t d;
  asm volatile("v_cvt_pk_bf16_f32 %0, %1, %2" : "=v"(d) : "v"(lo), "v"(hi));
  return d;
}
__device__ __forceinline__ f32x4 mfma16(bf16x8 a, bf16x8 b, f32x4 c) {
  return __builtin_amdgcn_mfma_f32_16x16x32_bf16(a, b, c, 0, 0, 0);
}
__device__ __forceinline__ void gload16(const unsigned short* src, unsigned short* dst) {
  __builtin_amdgcn_global_load_lds(
      (const __attribute__((address_space(1))) uint32_t*)src,
      (__attribute__((address_space(3))) uint32_t*)dst, 16, 0, 0);
}

// ---------------- fp32 -> bf16 convert ----------------
__global__ void cvt_kernel(const float* __restrict__ src, unsigned short* __restrict__ dst, int n4) {
  for (int i = blockIdx.x * blockDim.x + threadIdx.x; i < n4; i += gridDim.x * blockDim.x) {
    f32x4 v = ((const f32x4*)src)[i];
    u16x4 o;
    o[0] = f2bf(v[0]); o[1] = f2bf(v[1]); o[2] = f2bf(v[2]); o[3] = f2bf(v[3]);
    ((u16x4*)dst)[i] = o;
  }
}

// ---------------- GEMM: C[m][c] = sum_k A[m][k]*B[c][k] + bias[c] ----------------
// MODE 0: fp32 out C[m][1024] (out-proj).  MODE 1 (NN=3072): bf16 out via LDS-
// coalesced epilogue, routed per column region:
//   c in [0,1024)    -> qo[m][c] * 0.125 (exact)
//   c in [1024,2048) -> kto[n][h][l][d]
//   c in [2048,3072) -> vo[m][c-2048]
// Block walk: brow-outer / bcol-inner per XCD (A panel L2-reuse, B resident).
template<int MODE>
__global__ __launch_bounds__(256) void gemm_bt(
    const unsigned short* __restrict__ A, const unsigned short* __restrict__ B,
    const float* __restrict__ bias, float* __restrict__ Cf,
    unsigned short* __restrict__ qo, unsigned short* __restrict__ kto,
    unsigned short* __restrict__ vo)
{
  constexpr int NNc = (MODE == 1) ? 3072 : 1024;
  constexpr int BPX = NNc / 1024;            // bcols per XCD
  constexpr int KD  = 1024;

  __shared__ __align__(16) unsigned short smem[16384];   // 32 KB
  unsigned short* a_lds = smem;              // [128][32] during K-loop
  unsigned short* b_lds = smem + 4096;       // [128][32]

  const int bid = blockIdx.x;
  const int xcd = bid & 7;
  const int t = bid >> 3;
  const int brow = t / BPX;                  // compile-time div
  const int bcol = xcd * BPX + t % BPX;

  const int tid = threadIdx.x;
  const int w = tid >> 6, lane = tid & 63;
  const int wr = w >> 1, wc = w & 1;
  const int lrow = lane & 15, g = lane >> 4;

  f32x4 acc[4][4];
#pragma unroll
  for (int i = 0; i < 4; ++i)
#pragma unroll
    for (int j = 0; j < 4; ++j) acc[i][j] = (f32x4){0.f, 0.f, 0.f, 0.f};

  const int r_in = lane >> 2;
  const int u = lane & 3;

  auto stage = [&](int kt) {
    const size_t kcol = (size_t)kt * 32 + u * 8;
    gload16(A + (size_t)(brow * 128 + 16 * w + r_in) * KD + kcol,       &a_lds[(16 * w) * 32]);
    gload16(A + (size_t)(brow * 128 + 16 * (w + 4) + r_in) * KD + kcol, &a_lds[(16 * (w + 4)) * 32]);
    gload16(B + (size_t)(bcol * 128 + 16 * w + r_in) * KD + kcol,       &b_lds[(16 * w) * 32]);
    gload16(B + (size_t)(bcol * 128 + 16 * (w + 4) + r_in) * KD + kcol, &b_lds[(16 * (w + 4)) * 32]);
  };

  const int KT = KD >> 5;
  stage(0);
  for (int kt = 0; kt < KT; ++kt) {
    __syncthreads();
    bf16x8 af[4], bfr[4];
#pragma unroll
    for (int mt = 0; mt < 4; ++mt)
      af[mt] = *(const bf16x8*)&a_lds[(wr * 64 + mt * 16 + lrow) * 32 + g * 8];
#pragma unroll
    for (int nt = 0; nt < 4; ++nt)
      bfr[nt] = *(const bf16x8*)&b_lds[(wc * 64 + nt * 16 + lrow) * 32 + g * 8];
#pragma unroll
    for (int mt = 0; mt < 4; ++mt)
#pragma unroll
      for (int nt = 0; nt < 4; ++nt)
        acc[mt][nt] = mfma16(af[mt], bfr[nt], acc[mt][nt]);
    __syncthreads();                         // also fences last iter's LDS reads
    if (kt + 1 < KT) stage(kt + 1);
  }

  if (MODE == 0) {
    // fp32 scalar epilogue: 16 lanes x 4B = 64B runs, no amplification
#pragma unroll
    for (int nt = 0; nt < 4; ++nt) {
      const int c = bcol * 128 + wc * 64 + nt * 16 + lrow;
      const float bv = bias[c];
#pragma unroll
      for (int mt = 0; mt < 4; ++mt) {
        const int m0 = brow * 128 + wr * 64 + mt * 16 + g * 4;
#pragma unroll
        for (int j = 0; j < 4; ++j)
          Cf[(size_t)(m0 + j) * NNc + c] = acc[mt][nt][j] + bv;
      }
    }
  } else {
    // ---- coalesced bf16 epilogue via LDS bounce ----
    const float qs = (bcol < 8) ? 0.125f : 1.0f;   // uniform per block
#pragma unroll
    for (int nt = 0; nt < 4; ++nt) {
      const int c = bcol * 128 + wc * 64 + nt * 16 + lrow;
      const float bv = bias[c];
      const int lc = wc * 64 + nt * 16 + lrow;
#pragma unroll
      for (int mt = 0; mt < 4; ++mt) {
        const int lr0 = wr * 64 + mt * 16 + g * 4;
#pragma unroll
        for (int j = 0; j < 4; ++j)
          smem[(lr0 + j) * 128 + lc] = f2bf((acc[mt][nt][j] + bv) * qs);
      }
    }
    __syncthreads();
    // cooperative writer: 16 threads per row -> 256B contiguous runs
#pragma unroll
    for (int i = 0; i < 8; ++i) {
      const int unit = i * 256 + tid;        // 0..2047
      const int r = unit >> 4, cu = unit & 15;
      const u16x8 val = *(const u16x8*)&smem[r * 128 + cu * 8];
      const int m = brow * 128 + r;
      const int c = bcol * 128 + cu * 8;
      const int region = c >> 10, cl = c & 1023;
      if (region == 0)      *(u16x8*)&qo[(size_t)m * EE + cl] = val;
      else if (region == 2) *(u16x8*)&vo[(size_t)m * EE + cl] = val;
      else *(u16x8*)&kto[((size_t)((m & 7) * HH + (cl >> 6)) * LL + (m >> 3)) * DD + (cl & 63)] = val;
    }
  }
}

// ---------------- V transpose: v[m][1024] -> vt[n][h][d][s] ----------------
__global__ void transpose_v(const unsigned short* __restrict__ v, unsigned short* __restrict__ vt) {
  __shared__ __align__(16) unsigned short tile[64][68];
  const int b = blockIdx.x;                 // 2048
  const int lchunk = b & 15, h = (b >> 4) & 15, n = b >> 8;
  const int t = threadIdx.x;
  const int c4 = (t & 15) * 4, r = t >> 4;
#pragma unroll
  for (int p = 0; p < 4; ++p) {
    const int l = lchunk * 64 + p * 16 + r;
    u16x4 x = *(const u16x4*)&v[(size_t)(l * NB + n) * EE + h * DD + c4];
    *(u16x4*)&tile[p * 16 + r][c4] = x;
  }
  __syncthreads();
#pragma unroll
  for (int p = 0; p < 4; ++p) {
    const int d = p * 16 + r;
    u16x4 o;
#pragma unroll
    for (int i = 0; i < 4; ++i) o[i] = tile[c4 + i][d];
    *(u16x4*)&vt[((size_t)(n * HH + h) * DD + d) * LL + lchunk * 64 + c4] = o;
  }
}

// ---------------- flash attention (single pass, unnormalized accum) ----------------
// grid 1024 = n(8, XCD) x h(16) x ltile(8 of 128 rows); block 256 = 4 waves.
// Each wave owns TWO 16-row q-tiles: two independent QK->exp->PV chains for ILP.
// K chunk staged to LDS (XOR-swizzled source), double-buffered, 1 barrier/chunk.
__global__ __launch_bounds__(256) void attn_flash(
    const unsigned short* __restrict__ q,    // [m][1024] bf16, pre-scaled by 0.125
    const unsigned short* __restrict__ kt,   // [n][h][s][64]
    const unsigned short* __restrict__ vt,   // [n][h][64][1024]
    unsigned short* __restrict__ ctxo,       // [m][1024] bf16
    float* __restrict__ rinvb)               // [n][h][1024]
{
  __shared__ __align__(16) unsigned short kc[2][64][64];      // [buf][s][d], swizzled
  __shared__ __align__(16) unsigned short pl[4][2][16][72];   // [wave][tile][l][s]

  const int bid = blockIdx.x;
  const int n = bid & 7;
  const int rest = bid >> 3;        // 0..127
  const int h = rest >> 3;          // 0..15
  const int lt = (rest & 7) << 7;   // 0..896 step 128
  const int tid = threadIdx.x;
  const int wv = tid >> 6, lane = tid & 63;
  const int ll = lane & 15, g = lane >> 4;
  const int a3 = ll & 7;

  const int ltA = lt + wv * 16 + ll;
  const int ltB = lt + 64 + wv * 16 + ll;
  const unsigned short* qpA = q + ((size_t)ltA * NB + n) * EE + h * DD + g * 8;
  const unsigned short* qpB = q + ((size_t)ltB * NB + n) * EE + h * DD + g * 8;
  const bf16x8 qfA0 = *(const bf16x8*)qpA;
  const bf16x8 qfA1 = *(const bf16x8*)(qpA + 32);
  const bf16x8 qfB0 = *(const bf16x8*)qpB;
  const bf16x8 qfB1 = *(const bf16x8*)(qpB + 32);

  const unsigned short* kslab = kt + (size_t)(n * HH + h) * LL * DD;
  const unsigned short* vbase = vt + (size_t)(n * HH + h) * DD * LL;

  const int r8 = lane >> 3;
  const int c16 = (lane & 7) ^ r8;
  const int kof0 = ll * 128 + ((g ^ a3) << 4);        // k units 0..3
  const int kof1 = ll * 128 + (((4 + g) ^ a3) << 4);  // k units 4..7

  auto stageK = [&](int buf, int ch) {
    unsigned short* kd = &kc[buf][wv * 16][0];
    const unsigned short* src = kslab + (size_t)(ch * 64 + wv * 16) * DD;
    gload16(src + (size_t)r8 * DD + c16 * 8,       kd);
    gload16(src + (size_t)(8 + r8) * DD + c16 * 8, kd + 8 * 64);
  };

  f32x4 ctxA[4], ctxB[4];
#pragma unroll
  for (int i = 0; i < 4; ++i) { ctxA[i] = (f32x4){0.f,0.f,0.f,0.f}; ctxB[i] = (f32x4){0.f,0.f,0.f,0.f}; }
  f32x4 sumA = (f32x4){0.f,0.f,0.f,0.f}, sumB = (f32x4){0.f,0.f,0.f,0.f};

  char* plbA = (char*)&pl[wv][0][0][0];
  char* plbB = (char*)&pl[wv][1][0][0];

  stageK(0, 0);
  for (int ch = 0; ch < 16; ++ch) {
    __syncthreads();
    const int buf = ch & 1;
    const char* kb = (const char*)&kc[buf][0][0];

    bf16x8 vf0[4], vf1[4];
#pragma unroll
    for (int dt = 0; dt < 4; ++dt) {
      const unsigned short* vp = vbase + (size_t)(dt * 16 + ll) * LL + ch * 64 + g * 8;
      vf0[dt] = *(const bf16x8*)vp;
      vf1[dt] = *(const bf16x8*)(vp + 32);
    }

#pragma unroll
    for (int t = 0; t < 4; ++t) {
      bf16x8 kf0 = *(const bf16x8*)(kb + t * 2048 + kof0);
      bf16x8 kf1 = *(const bf16x8*)(kb + t * 2048 + kof1);
      f32x4 scA = (f32x4){0.f,0.f,0.f,0.f};
      f32x4 scB = (f32x4){0.f,0.f,0.f,0.f};
      scA = mfma16(kf0, qfA0, scA); scA = mfma16(kf1, qfA1, scA);
      scB = mfma16(kf0, qfB0, scB); scB = mfma16(kf1, qfB1, scB);
      f32x4 pA, pB;
#pragma unroll
      for (int j = 0; j < 4; ++j) { pA[j] = __expf(scA[j]); pB[j] = __expf(scB[j]); }
      sumA += pA; sumB += pB;
      uint2 wA; wA.x = cvtpk(pA[0], pA[1]); wA.y = cvtpk(pA[2], pA[3]);
      uint2 wB; wB.x = cvtpk(pB[0], pB[1]); wB.y = cvtpk(pB[2], pB[3]);
      *(uint2*)(plbA + ll * 144 + (t * 16 + g * 4) * 2) = wA;
      *(uint2*)(plbB + ll * 144 + (t * 16 + g * 4) * 2) = wB;
    }
    const bf16x8 pfA0 = *(const bf16x8*)(plbA + ll * 144 + g * 16);
    const bf16x8 pfA1 = *(const bf16x8*)(plbA + ll * 144 + 64 + g * 16);
    const bf16x8 pfB0 = *(const bf16x8*)(plbB + ll * 144 + g * 16);
    const bf16x8 pfB1 = *(const bf16x8*)(plbB + ll * 144 + 64 + g * 16);
#pragma unroll
    for (int dt = 0; dt < 4; ++dt) {
      ctxA[dt] = mfma16(vf0[dt], pfA0, ctxA[dt]);
      ctxA[dt] = mfma16(vf1[dt], pfA1, ctxA[dt]);
      ctxB[dt] = mfma16(vf0[dt], pfB0, ctxB[dt]);
      ctxB[dt] = mfma16(vf1[dt], pfB1, ctxB[dt]);
    }
    if (ch < 15) stageK(buf ^ 1, ch + 1);
  }

  float sA = sumA[0] + sumA[1] + sumA[2] + sumA[3];
  sA += __shfl_xor(sA, 16); sA += __shfl_xor(sA, 32);
  float sB = sumB[0] + sumB[1] + sumB[2] + sumB[3];
  sB += __shfl_xor(sB, 16); sB += __shfl_xor(sB, 32);
  const float rinvA = 1.0f / sA, rinvB = 1.0f / sB;
  if (lane < 16) {
    rinvb[(size_t)(n * HH + h) * LL + lt + wv * 16 + lane] = rinvA;
    rinvb[(size_t)(n * HH + h) * LL + lt + 64 + wv * 16 + lane] = rinvB;
  }

  unsigned short* cpA = ctxo + ((size_t)ltA * NB + n) * EE + h * DD;
  unsigned short* cpB = ctxo + ((size_t)ltB * NB + n) * EE + h * DD;
#pragma unroll
  for (int dt = 0; dt < 4; ++dt) {
    uint2 oA; oA.x = cvtpk(ctxA[dt][0]*rinvA, ctxA[dt][1]*rinvA);
    oA.y = cvtpk(ctxA[dt][2]*rinvA, ctxA[dt][3]*rinvA);
    uint2 oB; oB.x = cvtpk(ctxB[dt][0]*rinvB, ctxB[dt][1]*rinvB);
    oB.y = cvtpk(ctxB[dt][2]*rinvB, ctxB[dt][3]*rinvB);
    *(uint2*)(cpA + dt * 16 + g * 4) = oA;
    *(uint2*)(cpB + dt * 16 + g * 4) = oB;
  }
}

// ---------------- head-mean attention output (recompute QK with known rinv) ----------------
// grid 1024 = n(8, XCD) x [sh(8 of 128 s) x lt(16 of 64 rows)]; block 256 = 4 waves.
__global__ __launch_bounds__(256) void attn_mean(
    const unsigned short* __restrict__ q,    // [m][1024] bf16, pre-scaled by 0.125
    const unsigned short* __restrict__ kt,   // [n][h][s][64]
    const float* __restrict__ rinvb,         // [n][h][1024]
    float* __restrict__ attn_out)            // [n][1024][1024]
{
  __shared__ __align__(16) unsigned short kc[2][128][64];  // 32KB, swizzled

  const int bid = blockIdx.x;
  const int n = bid & 7;
  const int r = bid >> 3;                    // 0..127
  const int sh = r & 7;
  const int lt = (r >> 3) << 6;
  const int tid = threadIdx.x;
  const int wv = tid >> 6, lane = tid & 63;
  const int ll = lane & 15, g = lane >> 4;
  const int a3 = ll & 7;
  const int sb = sh << 7;
  const int lrow = lt + wv * 16 + ll;

  const int r8 = lane >> 3;
  const int c16 = (lane & 7) ^ r8;
  const int kof0 = ll * 128 + ((g ^ a3) << 4);
  const int kof1 = ll * 128 + (((4 + g) ^ a3) << 4);

  const unsigned short* kwin = kt + (size_t)n * HH * LL * DD + (size_t)sb * DD;

  auto stage = [&](int buf, int h) {
    unsigned short* kd = &kc[buf][wv * 32][0];
    const unsigned short* src = kwin + (size_t)h * LL * DD + (size_t)(wv * 32) * DD;
#pragma unroll
    for (int i = 0; i < 4; ++i)
      gload16(src + (size_t)(i * 8 + r8) * DD + c16 * 8, kd + i * 8 * 64);
  };

  float rv[16];
#pragma unroll
  for (int h = 0; h < HH; ++h) rv[h] = rinvb[(size_t)(n * HH + h) * LL + lrow];

  const unsigned short* qb2 = q + ((size_t)lrow * NB + n) * EE + g * 8;

  f32x4 acc[8];
#pragma unroll
  for (int i = 0; i < 8; ++i) acc[i] = (f32x4){0.f, 0.f, 0.f, 0.f};

  stage(0, 0);
  for (int h = 0; h < HH; ++h) {
    __syncthreads();
    const char* kb = (const char*)&kc[h & 1][0][0];
    const unsigned short* qp = qb2 + h * DD;
    const bf16x8 qf0 = *(const bf16x8*)qp;
    const bf16x8 qf1 = *(const bf16x8*)(qp + 32);
    const float rvh = rv[h];
#pragma unroll
    for (int t = 0; t < 8; ++t) {
      bf16x8 kf0 = *(const bf16x8*)(kb + t * 2048 + kof0);
      bf16x8 kf1 = *(const bf16x8*)(kb + t * 2048 + kof1);
      f32x4 sc = (f32x4){0.f, 0.f, 0.f, 0.f};
      sc = mfma16(kf0, qf0, sc);
      sc = mfma16(kf1, qf1, sc);
#pragma unroll
      for (int j = 0; j < 4; ++j) acc[t][j] += __expf(sc[j]) * rvh;
    }
    if (h + 1 < HH) stage((h + 1) & 1, h + 1);
  }

  float* ap = attn_out + ((size_t)n * LL + lrow) * LL + sb + g * 4;
#pragma unroll
  for (int t = 0; t < 8; ++t) *(f32x4*)(ap + t * 16) = acc[t] * 0.0625f;
}

extern "C" void kernel_launch(void* const* d_in, const int* in_sizes, int n_in,
                              void* d_out, int out_size, void* d_ws, size_t ws_size,
                              hipStream_t stream) {
  const float* x   = (const float*)d_in[0];
  const float* win = (const float*)d_in[1];
  const float* bin = (const float*)d_in[2];
  const float* ow  = (const float*)d_in[3];
  const float* ob  = (const float*)d_in[4];
  float* out = (float*)d_out;

  const size_t need = ((size_t)MM * EE * 5 + (size_t)K3 * EE + (size_t)EE * EE) * 2
                    + (size_t)NB * HH * LL * 4;
  if (ws_size < need) return;

  unsigned short* ws  = (unsigned short*)d_ws;
  unsigned short* xb  = ws;                        // [8192][1024]  (reused as ctx)
  unsigned short* wb  = xb + (size_t)MM * EE;      // [3072][1024]
  unsigned short* owb = wb + (size_t)K3 * EE;      // [1024][1024]
  unsigned short* qb  = owb + (size_t)EE * EE;     // [8192][1024]
  unsigned short* ktb = qb + (size_t)MM * EE;      // [8][16][1024][64]
  unsigned short* vb  = ktb + (size_t)MM * EE;     // [8192][1024]
  unsigned short* vtb = vb + (size_t)MM * EE;      // [8][16][64][1024]
  float* rinvb = (float*)(vtb + (size_t)MM * EE);  // [8][16][1024]
  unsigned short* ctx = xb;

  cvt_kernel<<<2048, 256, 0, stream>>>(x, xb, (MM * EE) / 4);
  cvt_kernel<<<1024, 256, 0, stream>>>(win, wb, (K3 * EE) / 4);
  cvt_kernel<<<512, 256, 0, stream>>>(ow, owb, (EE * EE) / 4);
  gemm_bt<1><<<64 * (K3 / 128), 256, 0, stream>>>(xb, wb, bin, nullptr, qb, ktb, vb);
  transpose_v<<<2048, 256, 0, stream>>>(vb, vtb);
  attn_flash<<<1024, 256, 0, stream>>>(qb, ktb, vtb, ctx, rinvb);
  attn_mean<<<1024, 256, 0, stream>>>(qb, ktb, rinvb, out + (size_t)MM * EE);
  gemm_bt<0><<<64 * (EE / 128), 256, 0, stream>>>(ctx, owb, ob, out, nullptr, nullptr, nullptr);
}

// Round 8
// 239.147 us; speedup vs baseline: 2.2639x; 1.0075x over previous
//
#include <hip/hip_runtime.h>
#include <stdint.h>

#define LL 1024
#define NB 8
#define EE 1024
#define HH 16
#define DD 64
#define MM (LL*NB)      // 8192 rows (l*NB+n)
#define K3 (3*EE)       // 3072

typedef __attribute__((ext_vector_type(8))) short bf16x8;   // 8 bf16 in 4 VGPRs
typedef __attribute__((ext_vector_type(4))) float f32x4;
typedef __attribute__((ext_vector_type(4))) unsigned short u16x4;
typedef __attribute__((ext_vector_type(8))) unsigned short u16x8;

__device__ __forceinline__ unsigned short f2bf(float f) {
  uint32_t u = __builtin_bit_cast(uint32_t, f);
  u += 0x7fffu + ((u >> 16) & 1u);           // RNE
  return (unsigned short)(u >> 16);
}
// HW RNE pack: dst = [bf16(hi)|bf16(lo)] — bit-identical to f2bf pairs
__device__ __forceinline__ uint32_t cvtpk(float lo, float hi) {
  uint32_t d;
  asm volatile("v_cvt_pk_bf16_f32 %0, %1, %2" : "=v"(d) : "v"(lo), "v"(hi));
  return d;
}
__device__ __forceinline__ f32x4 mfma16(bf16x8 a, bf16x8 b, f32x4 c) {
  return __builtin_amdgcn_mfma_f32_16x16x32_bf16(a, b, c, 0, 0, 0);
}
__device__ __forceinline__ void gload16(const unsigned short* src, unsigned short* dst) {
  __builtin_amdgcn_global_load_lds(
      (const __attribute__((address_space(1))) uint32_t*)src,
      (__attribute__((address_space(3))) uint32_t*)dst, 16, 0, 0);
}

// ---------------- fp32 -> bf16 convert ----------------
__global__ void cvt_kernel(const float* __restrict__ src, unsigned short* __restrict__ dst, int n4) {
  for (int i = blockIdx.x * blockDim.x + threadIdx.x; i < n4; i += gridDim.x * blockDim.x) {
    f32x4 v = ((const f32x4*)src)[i];
    u16x4 o;
    o[0] = f2bf(v[0]); o[1] = f2bf(v[1]); o[2] = f2bf(v[2]); o[3] = f2bf(v[3]);
    ((u16x4*)dst)[i] = o;
  }
}

// ---------------- GEMM: C[m][c] = sum_k A[m][k]*B[c][k] + bias[c] ----------------
// Double-buffered LDS tiles (32 KB), stage issued right after the single
// per-K-step barrier (latency covered by ds_read+MFMA of current tile).
// MODE 0: fp32 out C[m][1024].  MODE 1 (NN=3072): bf16 out via LDS-coalesced
// epilogue (unions the tile buffers), routed per column region:
//   c in [0,1024)    -> qo[m][c] * 0.125 (exact)
//   c in [1024,2048) -> kto[n][h][l][d]
//   c in [2048,3072) -> vo[m][c-2048]
template<int MODE>
__global__ __launch_bounds__(256) void gemm_bt(
    const unsigned short* __restrict__ A, const unsigned short* __restrict__ B,
    const float* __restrict__ bias, float* __restrict__ Cf,
    unsigned short* __restrict__ qo, unsigned short* __restrict__ kto,
    unsigned short* __restrict__ vo)
{
  constexpr int NNc = (MODE == 1) ? 3072 : 1024;
  constexpr int BPX = NNc / 1024;            // bcols per XCD
  constexpr int KD  = 1024;

  __shared__ __align__(16) unsigned short smem[16384];   // 32 KB: a0|b0|a1|b1

  const int bid = blockIdx.x;
  const int xcd = bid & 7;
  const int t = bid >> 3;
  const int brow = t / BPX;
  const int bcol = xcd * BPX + t % BPX;

  const int tid = threadIdx.x;
  const int w = tid >> 6, lane = tid & 63;
  const int wr = w >> 1, wc = w & 1;
  const int lrow = lane & 15, g = lane >> 4;

  f32x4 acc[4][4];
#pragma unroll
  for (int i = 0; i < 4; ++i)
#pragma unroll
    for (int j = 0; j < 4; ++j) acc[i][j] = (f32x4){0.f, 0.f, 0.f, 0.f};

  const int r_in = lane >> 2;
  const int u = lane & 3;

  auto stage = [&](int kt) {
    unsigned short* a_lds = smem + ((kt & 1) ? 8192 : 0);
    unsigned short* b_lds = a_lds + 4096;
    const size_t kcol = (size_t)kt * 32 + u * 8;
    gload16(A + (size_t)(brow * 128 + 16 * w + r_in) * KD + kcol,       &a_lds[(16 * w) * 32]);
    gload16(A + (size_t)(brow * 128 + 16 * (w + 4) + r_in) * KD + kcol, &a_lds[(16 * (w + 4)) * 32]);
    gload16(B + (size_t)(bcol * 128 + 16 * w + r_in) * KD + kcol,       &b_lds[(16 * w) * 32]);
    gload16(B + (size_t)(bcol * 128 + 16 * (w + 4) + r_in) * KD + kcol, &b_lds[(16 * (w + 4)) * 32]);
  };

  const int KT = KD >> 5;
  stage(0);
  for (int kt = 0; kt < KT; ++kt) {
    __syncthreads();                         // buf[kt&1] staged; prev reads joined
    if (kt + 1 < KT) stage(kt + 1);          // early prefetch into buf^1
    const unsigned short* a_lds = smem + ((kt & 1) ? 8192 : 0);
    const unsigned short* b_lds = a_lds + 4096;
    bf16x8 af[4], bfr[4];
#pragma unroll
    for (int mt = 0; mt < 4; ++mt)
      af[mt] = *(const bf16x8*)&a_lds[(wr * 64 + mt * 16 + lrow) * 32 + g * 8];
#pragma unroll
    for (int nt = 0; nt < 4; ++nt)
      bfr[nt] = *(const bf16x8*)&b_lds[(wc * 64 + nt * 16 + lrow) * 32 + g * 8];
#pragma unroll
    for (int mt = 0; mt < 4; ++mt)
#pragma unroll
      for (int nt = 0; nt < 4; ++nt)
        acc[mt][nt] = mfma16(af[mt], bfr[nt], acc[mt][nt]);
  }

  if (MODE == 0) {
#pragma unroll
    for (int nt = 0; nt < 4; ++nt) {
      const int c = bcol * 128 + wc * 64 + nt * 16 + lrow;
      const float bv = bias[c];
#pragma unroll
      for (int mt = 0; mt < 4; ++mt) {
        const int m0 = brow * 128 + wr * 64 + mt * 16 + g * 4;
#pragma unroll
        for (int j = 0; j < 4; ++j)
          Cf[(size_t)(m0 + j) * NNc + c] = acc[mt][nt][j] + bv;
      }
    }
  } else {
    __syncthreads();                         // all tile reads done before reuse
    const float qs = (bcol < 8) ? 0.125f : 1.0f;
#pragma unroll
    for (int nt = 0; nt < 4; ++nt) {
      const int c = bcol * 128 + wc * 64 + nt * 16 + lrow;
      const float bv = bias[c];
      const int lc = wc * 64 + nt * 16 + lrow;
#pragma unroll
      for (int mt = 0; mt < 4; ++mt) {
        const int lr0 = wr * 64 + mt * 16 + g * 4;
#pragma unroll
        for (int j = 0; j < 4; ++j)
          smem[(lr0 + j) * 128 + lc] = f2bf((acc[mt][nt][j] + bv) * qs);
      }
    }
    __syncthreads();
#pragma unroll
    for (int i = 0; i < 8; ++i) {
      const int unit = i * 256 + tid;        // 0..2047
      const int r = unit >> 4, cu = unit & 15;
      const u16x8 val = *(const u16x8*)&smem[r * 128 + cu * 8];
      const int m = brow * 128 + r;
      const int c = bcol * 128 + cu * 8;
      const int region = c >> 10, cl = c & 1023;
      if (region == 0)      *(u16x8*)&qo[(size_t)m * EE + cl] = val;
      else if (region == 2) *(u16x8*)&vo[(size_t)m * EE + cl] = val;
      else *(u16x8*)&kto[((size_t)((m & 7) * HH + (cl >> 6)) * LL + (m >> 3)) * DD + (cl & 63)] = val;
    }
  }
}

// ---------------- V transpose: v[m][1024] -> vt[n][h][d][s] ----------------
__global__ void transpose_v(const unsigned short* __restrict__ v, unsigned short* __restrict__ vt) {
  __shared__ __align__(16) unsigned short tile[64][68];
  const int b = blockIdx.x;                 // 2048
  const int lchunk = b & 15, h = (b >> 4) & 15, n = b >> 8;
  const int t = threadIdx.x;
  const int c4 = (t & 15) * 4, r = t >> 4;
#pragma unroll
  for (int p = 0; p < 4; ++p) {
    const int l = lchunk * 64 + p * 16 + r;
    u16x4 x = *(const u16x4*)&v[(size_t)(l * NB + n) * EE + h * DD + c4];
    *(u16x4*)&tile[p * 16 + r][c4] = x;
  }
  __syncthreads();
#pragma unroll
  for (int p = 0; p < 4; ++p) {
    const int d = p * 16 + r;
    u16x4 o;
#pragma unroll
    for (int i = 0; i < 4; ++i) o[i] = tile[c4 + i][d];
    *(u16x4*)&vt[((size_t)(n * HH + h) * DD + d) * LL + lchunk * 64 + c4] = o;
  }
}

// ---------------- flash attention (single pass, unnormalized accum) ----------------
// grid 1024 = n(8, XCD) x h(16) x ltile(8 of 128 rows); block 256 = 4 waves.
// Each wave owns TWO 16-row q-tiles: two independent QK->exp->PV chains for ILP.
// K chunk staged to LDS (XOR-swizzled source), double-buffered; next-chunk stage
// issued right after the barrier (after V loads) so the full body covers latency.
__global__ __launch_bounds__(256) void attn_flash(
    const unsigned short* __restrict__ q,    // [m][1024] bf16, pre-scaled by 0.125
    const unsigned short* __restrict__ kt,   // [n][h][s][64]
    const unsigned short* __restrict__ vt,   // [n][h][64][1024]
    unsigned short* __restrict__ ctxo,       // [m][1024] bf16
    float* __restrict__ rinvb)               // [n][h][1024]
{
  __shared__ __align__(16) unsigned short kc[2][64][64];      // [buf][s][d], swizzled
  __shared__ __align__(16) unsigned short pl[4][2][16][72];   // [wave][tile][l][s]

  const int bid = blockIdx.x;
  const int n = bid & 7;
  const int rest = bid >> 3;        // 0..127
  const int h = rest >> 3;          // 0..15
  const int lt = (rest & 7) << 7;   // 0..896 step 128
  const int tid = threadIdx.x;
  const int wv = tid >> 6, lane = tid & 63;
  const int ll = lane & 15, g = lane >> 4;
  const int a3 = ll & 7;

  const int ltA = lt + wv * 16 + ll;
  const int ltB = lt + 64 + wv * 16 + ll;
  const unsigned short* qpA = q + ((size_t)ltA * NB + n) * EE + h * DD + g * 8;
  const unsigned short* qpB = q + ((size_t)ltB * NB + n) * EE + h * DD + g * 8;
  const bf16x8 qfA0 = *(const bf16x8*)qpA;
  const bf16x8 qfA1 = *(const bf16x8*)(qpA + 32);
  const bf16x8 qfB0 = *(const bf16x8*)qpB;
  const bf16x8 qfB1 = *(const bf16x8*)(qpB + 32);

  const unsigned short* kslab = kt + (size_t)(n * HH + h) * LL * DD;
  const unsigned short* vbase = vt + (size_t)(n * HH + h) * DD * LL;

  const int r8 = lane >> 3;
  const int c16 = (lane & 7) ^ r8;
  const int kof0 = ll * 128 + ((g ^ a3) << 4);        // k units 0..3
  const int kof1 = ll * 128 + (((4 + g) ^ a3) << 4);  // k units 4..7

  auto stageK = [&](int buf, int ch) {
    unsigned short* kd = &kc[buf][wv * 16][0];
    const unsigned short* src = kslab + (size_t)(ch * 64 + wv * 16) * DD;
    gload16(src + (size_t)r8 * DD + c16 * 8,       kd);
    gload16(src + (size_t)(8 + r8) * DD + c16 * 8, kd + 8 * 64);
  };

  f32x4 ctxA[4], ctxB[4];
#pragma unroll
  for (int i = 0; i < 4; ++i) { ctxA[i] = (f32x4){0.f,0.f,0.f,0.f}; ctxB[i] = (f32x4){0.f,0.f,0.f,0.f}; }
  f32x4 sumA = (f32x4){0.f,0.f,0.f,0.f}, sumB = (f32x4){0.f,0.f,0.f,0.f};

  char* plbA = (char*)&pl[wv][0][0][0];
  char* plbB = (char*)&pl[wv][1][0][0];

  stageK(0, 0);
  for (int ch = 0; ch < 16; ++ch) {
    __syncthreads();                 // buf[ch&1] staged; prev iter's reads joined
    const int buf = ch & 1;
    const char* kb = (const char*)&kc[buf][0][0];

    // V loads first (consumed at PV this iter -> their waitcnt won't drain stage)
    bf16x8 vf0[4], vf1[4];
#pragma unroll
    for (int dt = 0; dt < 4; ++dt) {
      const unsigned short* vp = vbase + (size_t)(dt * 16 + ll) * LL + ch * 64 + g * 8;
      vf0[dt] = *(const bf16x8*)vp;
      vf1[dt] = *(const bf16x8*)(vp + 32);
    }
    if (ch < 15) stageK(buf ^ 1, ch + 1);   // early prefetch, covered by QK+exp+PV

#pragma unroll
    for (int t = 0; t < 4; ++t) {
      bf16x8 kf0 = *(const bf16x8*)(kb + t * 2048 + kof0);
      bf16x8 kf1 = *(const bf16x8*)(kb + t * 2048 + kof1);
      f32x4 scA = (f32x4){0.f,0.f,0.f,0.f};
      f32x4 scB = (f32x4){0.f,0.f,0.f,0.f};
      scA = mfma16(kf0, qfA0, scA); scA = mfma16(kf1, qfA1, scA);
      scB = mfma16(kf0, qfB0, scB); scB = mfma16(kf1, qfB1, scB);
      f32x4 pA, pB;
#pragma unroll
      for (int j = 0; j < 4; ++j) { pA[j] = __expf(scA[j]); pB[j] = __expf(scB[j]); }
      sumA += pA; sumB += pB;
      uint2 wA; wA.x = cvtpk(pA[0], pA[1]); wA.y = cvtpk(pA[2], pA[3]);
      uint2 wB; wB.x = cvtpk(pB[0], pB[1]); wB.y = cvtpk(pB[2], pB[3]);
      *(uint2*)(plbA + ll * 144 + (t * 16 + g * 4) * 2) = wA;
      *(uint2*)(plbB + ll * 144 + (t * 16 + g * 4) * 2) = wB;
    }
    const bf16x8 pfA0 = *(const bf16x8*)(plbA + ll * 144 + g * 16);
    const bf16x8 pfA1 = *(const bf16x8*)(plbA + ll * 144 + 64 + g * 16);
    const bf16x8 pfB0 = *(const bf16x8*)(plbB + ll * 144 + g * 16);
    const bf16x8 pfB1 = *(const bf16x8*)(plbB + ll * 144 + 64 + g * 16);
#pragma unroll
    for (int dt = 0; dt < 4; ++dt) {
      ctxA[dt] = mfma16(vf0[dt], pfA0, ctxA[dt]);
      ctxA[dt] = mfma16(vf1[dt], pfA1, ctxA[dt]);
      ctxB[dt] = mfma16(vf0[dt], pfB0, ctxB[dt]);
      ctxB[dt] = mfma16(vf1[dt], pfB1, ctxB[dt]);
    }
  }

  float sA = sumA[0] + sumA[1] + sumA[2] + sumA[3];
  sA += __shfl_xor(sA, 16); sA += __shfl_xor(sA, 32);
  float sB = sumB[0] + sumB[1] + sumB[2] + sumB[3];
  sB += __shfl_xor(sB, 16); sB += __shfl_xor(sB, 32);
  const float rinvA = 1.0f / sA, rinvB = 1.0f / sB;
  if (lane < 16) {
    rinvb[(size_t)(n * HH + h) * LL + lt + wv * 16 + lane] = rinvA;
    rinvb[(size_t)(n * HH + h) * LL + lt + 64 + wv * 16 + lane] = rinvB;
  }

  unsigned short* cpA = ctxo + ((size_t)ltA * NB + n) * EE + h * DD;
  unsigned short* cpB = ctxo + ((size_t)ltB * NB + n) * EE + h * DD;
#pragma unroll
  for (int dt = 0; dt < 4; ++dt) {
    uint2 oA; oA.x = cvtpk(ctxA[dt][0]*rinvA, ctxA[dt][1]*rinvA);
    oA.y = cvtpk(ctxA[dt][2]*rinvA, ctxA[dt][3]*rinvA);
    uint2 oB; oB.x = cvtpk(ctxB[dt][0]*rinvB, ctxB[dt][1]*rinvB);
    oB.y = cvtpk(ctxB[dt][2]*rinvB, ctxB[dt][3]*rinvB);
    *(uint2*)(cpA + dt * 16 + g * 4) = oA;
    *(uint2*)(cpB + dt * 16 + g * 4) = oB;
  }
}

// ---------------- head-mean attention output (recompute QK with known rinv) ----------------
// grid 1024 = n(8, XCD) x [sh(8 of 128 s) x lt(16 of 64 rows)]; block 256 = 4 waves.
// Next-head K stage issued right after the barrier (after q loads).
__global__ __launch_bounds__(256) void attn_mean(
    const unsigned short* __restrict__ q,    // [m][1024] bf16, pre-scaled by 0.125
    const unsigned short* __restrict__ kt,   // [n][h][s][64]
    const float* __restrict__ rinvb,         // [n][h][1024]
    float* __restrict__ attn_out)            // [n][1024][1024]
{
  __shared__ __align__(16) unsigned short kc[2][128][64];  // 32KB, swizzled

  const int bid = blockIdx.x;
  const int n = bid & 7;
  const int r = bid >> 3;                    // 0..127
  const int sh = r & 7;
  const int lt = (r >> 3) << 6;
  const int tid = threadIdx.x;
  const int wv = tid >> 6, lane = tid & 63;
  const int ll = lane & 15, g = lane >> 4;
  const int a3 = ll & 7;
  const int sb = sh << 7;
  const int lrow = lt + wv * 16 + ll;

  const int r8 = lane >> 3;
  const int c16 = (lane & 7) ^ r8;
  const int kof0 = ll * 128 + ((g ^ a3) << 4);
  const int kof1 = ll * 128 + (((4 + g) ^ a3) << 4);

  const unsigned short* kwin = kt + (size_t)n * HH * LL * DD + (size_t)sb * DD;

  auto stage = [&](int buf, int h) {
    unsigned short* kd = &kc[buf][wv * 32][0];
    const unsigned short* src = kwin + (size_t)h * LL * DD + (size_t)(wv * 32) * DD;
#pragma unroll
    for (int i = 0; i < 4; ++i)
      gload16(src + (size_t)(i * 8 + r8) * DD + c16 * 8, kd + i * 8 * 64);
  };

  float rv[16];
#pragma unroll
  for (int h = 0; h < HH; ++h) rv[h] = rinvb[(size_t)(n * HH + h) * LL + lrow];

  const unsigned short* qb2 = q + ((size_t)lrow * NB + n) * EE + g * 8;

  f32x4 acc[8];
#pragma unroll
  for (int i = 0; i < 8; ++i) acc[i] = (f32x4){0.f, 0.f, 0.f, 0.f};

  stage(0, 0);
  for (int h = 0; h < HH; ++h) {
    __syncthreads();                 // buf[h&1] staged; prev reads joined
    const char* kb = (const char*)&kc[h & 1][0][0];
    const unsigned short* qp = qb2 + h * DD;
    const bf16x8 qf0 = *(const bf16x8*)qp;   // q loads first (consumed this iter)
    const bf16x8 qf1 = *(const bf16x8*)(qp + 32);
    if (h + 1 < HH) stage((h + 1) & 1, h + 1);   // early prefetch
    const float rvh = rv[h];
#pragma unroll
    for (int t = 0; t < 8; ++t) {
      bf16x8 kf0 = *(const bf16x8*)(kb + t * 2048 + kof0);
      bf16x8 kf1 = *(const bf16x8*)(kb + t * 2048 + kof1);
      f32x4 sc = (f32x4){0.f, 0.f, 0.f, 0.f};
      sc = mfma16(kf0, qf0, sc);
      sc = mfma16(kf1, qf1, sc);
#pragma unroll
      for (int j = 0; j < 4; ++j) acc[t][j] += __expf(sc[j]) * rvh;
    }
  }

  float* ap = attn_out + ((size_t)n * LL + lrow) * LL + sb + g * 4;
#pragma unroll
  for (int t = 0; t < 8; ++t) *(f32x4*)(ap + t * 16) = acc[t] * 0.0625f;
}

extern "C" void kernel_launch(void* const* d_in, const int* in_sizes, int n_in,
                              void* d_out, int out_size, void* d_ws, size_t ws_size,
                              hipStream_t stream) {
  const float* x   = (const float*)d_in[0];
  const float* win = (const float*)d_in[1];
  const float* bin = (const float*)d_in[2];
  const float* ow  = (const float*)d_in[3];
  const float* ob  = (const float*)d_in[4];
  float* out = (float*)d_out;

  const size_t need = ((size_t)MM * EE * 5 + (size_t)K3 * EE + (size_t)EE * EE) * 2
                    + (size_t)NB * HH * LL * 4;
  if (ws_size < need) return;

  unsigned short* ws  = (unsigned short*)d_ws;
  unsigned short* xb  = ws;                        // [8192][1024]  (reused as ctx)
  unsigned short* wb  = xb + (size_t)MM * EE;      // [3072][1024]
  unsigned short* owb = wb + (size_t)K3 * EE;      // [1024][1024]
  unsigned short* qb  = owb + (size_t)EE * EE;     // [8192][1024]
  unsigned short* ktb = qb + (size_t)MM * EE;      // [8][16][1024][64]
  unsigned short* vb  = ktb + (size_t)MM * EE;     // [8192][1024]
  unsigned short* vtb = vb + (size_t)MM * EE;      // [8][16][64][1024]
  float* rinvb = (float*)(vtb + (size_t)MM * EE);  // [8][16][1024]
  unsigned short* ctx = xb;

  cvt_kernel<<<2048, 256, 0, stream>>>(x, xb, (MM * EE) / 4);
  cvt_kernel<<<1024, 256, 0, stream>>>(win, wb, (K3 * EE) / 4);
  cvt_kernel<<<512, 256, 0, stream>>>(ow, owb, (EE * EE) / 4);
  gemm_bt<1><<<64 * (K3 / 128), 256, 0, stream>>>(xb, wb, bin, nullptr, qb, ktb, vb);
  transpose_v<<<2048, 256, 0, stream>>>(vb, vtb);
  attn_flash<<<1024, 256, 0, stream>>>(qb, ktb, vtb, ctx, rinvb);
  attn_mean<<<1024, 256, 0, stream>>>(qb, ktb, rinvb, out + (size_t)MM * EE);
  gemm_bt<0><<<64 * (EE / 128), 256, 0, stream>>>(ctx, owb, ob, out, nullptr, nullptr, nullptr);
}